// Round 1
// baseline (1775.104 us; speedup 1.0000x reference)
//
#include <hip/hip_runtime.h>

#define N_ENT   100000
#define N_REL   500
#define N_EDGES 800000
#define DIM     128
#define WA_LD   384

// ---------------------------------------------------------------------------
// K1: PR[r][j] = ba[j] + sum_k rel[r][k] * Wa[j][128+k]   (500 x 128)
// one block (128 threads) per relation
__global__ __launch_bounds__(128) void k_rel(const float* __restrict__ rel,
                                             const float* __restrict__ Wa,
                                             const float* __restrict__ ba,
                                             float* __restrict__ PR) {
    int r = blockIdx.x;
    int j = threadIdx.x;
    __shared__ float relrow[DIM];
    relrow[j] = rel[r * DIM + j];
    __syncthreads();
    const float* wrow = Wa + (size_t)j * WA_LD + 128;
    float acc = ba[j];
#pragma unroll 8
    for (int k = 0; k < DIM; ++k) acc += relrow[k] * wrow[k];
    PR[r * DIM + j] = acc;
}

// ---------------------------------------------------------------------------
// K2: PH = ent @ Wa_h^T, PT = ent @ Wa_t^T (100000 x 128 each)
// 256 threads: 8 row-groups x 32 col-threads; 4 rows/thread, 4 cols/thread
// LDS: WaTh[k][j], WaTt[k][j] (64KB each) + 32 staged ent rows (16KB)
__global__ __launch_bounds__(256) void k_ent(const float* __restrict__ ent,
                                             const float* __restrict__ Wa,
                                             float* __restrict__ PH,
                                             float* __restrict__ PT) {
    __shared__ float WaTh[DIM][DIM];
    __shared__ float WaTt[DIM][DIM];
    __shared__ float rows[32][DIM];
    int t = threadIdx.x;

    // load Wa transposed (coalesced reads of Wa rows)
    for (int idx = t; idx < DIM * DIM; idx += 256) {
        int j = idx >> 7, k = idx & 127;
        WaTh[k][j] = Wa[(size_t)j * WA_LD + k];
        WaTt[k][j] = Wa[(size_t)j * WA_LD + 256 + k];
    }
    int row0 = blockIdx.x * 32;
    for (int idx = t; idx < 32 * DIM; idx += 256) {
        int rr = idx >> 7, k = idx & 127;
        int grow = row0 + rr;
        rows[rr][k] = (grow < N_ENT) ? ent[(size_t)grow * DIM + k] : 0.f;
    }
    __syncthreads();

    int jc = (t & 31) * 4;
    int rg = t >> 5;     // 0..7
    float4 accH[4], accT[4];
#pragma unroll
    for (int r = 0; r < 4; ++r) {
        accH[r] = make_float4(0.f, 0.f, 0.f, 0.f);
        accT[r] = make_float4(0.f, 0.f, 0.f, 0.f);
    }

    for (int k = 0; k < DIM; ++k) {
        float4 wh = *(const float4*)&WaTh[k][jc];
        float4 wt = *(const float4*)&WaTt[k][jc];
#pragma unroll
        for (int r = 0; r < 4; ++r) {
            float e = rows[rg * 4 + r][k];
            accH[r].x += e * wh.x; accH[r].y += e * wh.y;
            accH[r].z += e * wh.z; accH[r].w += e * wh.w;
            accT[r].x += e * wt.x; accT[r].y += e * wt.y;
            accT[r].z += e * wt.z; accT[r].w += e * wt.w;
        }
    }

#pragma unroll
    for (int r = 0; r < 4; ++r) {
        int grow = row0 + rg * 4 + r;
        if (grow < N_ENT) {
            *(float4*)&PH[(size_t)grow * DIM + jc] = accH[r];
            *(float4*)&PT[(size_t)grow * DIM + jc] = accT[r];
        }
    }
}

// ---------------------------------------------------------------------------
// K3: per edge: c = PH[h] + PR[r] + PT[t]; b = dot(c,Wa2)+ba2;
//     w = exp(leaky_relu(b)); atomic hs[h] += w*c; ebs[h] += w
// 32 lanes per edge, 4 cols per lane
__global__ __launch_bounds__(256) void k_edge(const int* __restrict__ trip,
                                              const float* __restrict__ PH,
                                              const float* __restrict__ PR,
                                              const float* __restrict__ PT,
                                              const float* __restrict__ Wa2,
                                              const float* __restrict__ ba2,
                                              float* __restrict__ hs,
                                              float* __restrict__ ebs) {
    int t = threadIdx.x;
    int lane = t & 31;
    int grp = (int)((blockIdx.x * blockDim.x + t) >> 5);
    int ngrp = (int)((gridDim.x * blockDim.x) >> 5);
    float4 w2 = *(const float4*)&Wa2[lane * 4];
    float bb2 = ba2[0];

    for (int e = grp; e < N_EDGES; e += ngrp) {
        int h  = trip[e * 3 + 0];
        int tl = trip[e * 3 + 1];
        int r  = trip[e * 3 + 2];
        float4 ph = *(const float4*)&PH[(size_t)h  * DIM + lane * 4];
        float4 pr = *(const float4*)&PR[(size_t)r  * DIM + lane * 4];
        float4 pt = *(const float4*)&PT[(size_t)tl * DIM + lane * 4];
        float4 c;
        c.x = ph.x + pr.x + pt.x;
        c.y = ph.y + pr.y + pt.y;
        c.z = ph.z + pr.z + pt.z;
        c.w = ph.w + pr.w + pt.w;
        float p = c.x * w2.x + c.y * w2.y + c.z * w2.z + c.w * w2.w;
#pragma unroll
        for (int m = 1; m <= 16; m <<= 1) p += __shfl_xor(p, m);
        float b = p + bb2;
        float lr = b > 0.f ? b : 0.01f * b;
        float w = expf(lr);
        float* dst = &hs[(size_t)h * DIM + lane * 4];
        atomicAdd(dst + 0, w * c.x);
        atomicAdd(dst + 1, w * c.y);
        atomicAdd(dst + 2, w * c.z);
        atomicAdd(dst + 3, w * c.w);
        if (lane == 0) atomicAdd(&ebs[h], w);
    }
}

// ---------------------------------------------------------------------------
// K4: out = elu(hs / ebs'), in place on d_out
__global__ __launch_bounds__(256) void k_fin(float* __restrict__ out,
                                             const float* __restrict__ ebs) {
    int idx = blockIdx.x * blockDim.x + threadIdx.x;
    int i = idx >> 5;
    int lane = idx & 31;
    if (i >= N_ENT) return;
    float den = ebs[i];
    den = (den == 0.f) ? 1e-12f : den;
    float inv = 1.f / den;
    float4 v = *(float4*)&out[(size_t)i * DIM + lane * 4];
    v.x *= inv; v.y *= inv; v.z *= inv; v.w *= inv;
    v.x = v.x > 0.f ? v.x : expm1f(v.x);
    v.y = v.y > 0.f ? v.y : expm1f(v.y);
    v.z = v.z > 0.f ? v.z : expm1f(v.z);
    v.w = v.w > 0.f ? v.w : expm1f(v.w);
    *(float4*)&out[(size_t)i * DIM + lane * 4] = v;
}

// ---------------------------------------------------------------------------
extern "C" void kernel_launch(void* const* d_in, const int* in_sizes, int n_in,
                              void* d_out, int out_size, void* d_ws, size_t ws_size,
                              hipStream_t stream) {
    const int*   trip = (const int*)d_in[0];
    const float* ent  = (const float*)d_in[1];
    const float* rel  = (const float*)d_in[2];
    const float* Wa   = (const float*)d_in[3];
    const float* ba   = (const float*)d_in[4];
    const float* Wa2  = (const float*)d_in[5];
    const float* ba2  = (const float*)d_in[6];
    float* out = (float*)d_out;

    char* ws = (char*)d_ws;
    const size_t PH_BYTES = (size_t)N_ENT * DIM * 4;   // 51.2 MB
    float* PH  = (float*)ws;
    float* PT  = (float*)(ws + PH_BYTES);
    float* PR  = (float*)(ws + 2 * PH_BYTES);
    float* ebs = (float*)(ws + 2 * PH_BYTES + (size_t)N_REL * DIM * 4);

    hipMemsetAsync(out, 0, PH_BYTES, stream);
    hipMemsetAsync(ebs, 0, (size_t)N_ENT * 4, stream);

    k_rel<<<N_REL, 128, 0, stream>>>(rel, Wa, ba, PR);
    k_ent<<<(N_ENT + 31) / 32, 256, 0, stream>>>(ent, Wa, PH, PT);
    k_edge<<<2048, 256, 0, stream>>>(trip, PH, PR, PT, Wa2, ba2, out, ebs);
    k_fin<<<(N_ENT * 32 + 255) / 256, 256, 0, stream>>>(out, ebs);
}

// Round 2
// 745.570 us; speedup vs baseline: 2.3809x; 2.3809x over previous
//
#include <hip/hip_runtime.h>

#define N_ENT   100000
#define N_REL   500
#define N_EDGES 800000
#define DIM     128
#define WA_LD   384

// ---------------------------------------------------------------------------
// K1: PR[r][j] = ba[j] + sum_k rel[r][k] * Wa[j][128+k]; qr[r] = dot(PR[r], Wa2)
__global__ __launch_bounds__(128) void k_rel(const float* __restrict__ rel,
                                             const float* __restrict__ Wa,
                                             const float* __restrict__ ba,
                                             const float* __restrict__ Wa2,
                                             float* __restrict__ PR,
                                             float* __restrict__ qr) {
    int r = blockIdx.x;
    int j = threadIdx.x;
    __shared__ float relrow[DIM];
    __shared__ float red[DIM];
    relrow[j] = rel[r * DIM + j];
    __syncthreads();
    const float* wrow = Wa + (size_t)j * WA_LD + 128;
    float acc = ba[j];
#pragma unroll 8
    for (int k = 0; k < DIM; ++k) acc += relrow[k] * wrow[k];
    PR[r * DIM + j] = acc;
    red[j] = acc * Wa2[j];
    __syncthreads();
    for (int s = 64; s > 0; s >>= 1) {
        if (j < s) red[j] += red[j + s];
        __syncthreads();
    }
    if (j == 0) qr[r] = red[0];
}

// ---------------------------------------------------------------------------
// K2: PH = ent @ Wa_h^T, PT = ent @ Wa_t^T (unchanged from round 0)
__global__ __launch_bounds__(256) void k_ent(const float* __restrict__ ent,
                                             const float* __restrict__ Wa,
                                             float* __restrict__ PH,
                                             float* __restrict__ PT) {
    __shared__ float WaTh[DIM][DIM];
    __shared__ float WaTt[DIM][DIM];
    __shared__ float rows[32][DIM];
    int t = threadIdx.x;

    for (int idx = t; idx < DIM * DIM; idx += 256) {
        int j = idx >> 7, k = idx & 127;
        WaTh[k][j] = Wa[(size_t)j * WA_LD + k];
        WaTt[k][j] = Wa[(size_t)j * WA_LD + 256 + k];
    }
    int row0 = blockIdx.x * 32;
    for (int idx = t; idx < 32 * DIM; idx += 256) {
        int rr = idx >> 7, k = idx & 127;
        int grow = row0 + rr;
        rows[rr][k] = (grow < N_ENT) ? ent[(size_t)grow * DIM + k] : 0.f;
    }
    __syncthreads();

    int jc = (t & 31) * 4;
    int rg = t >> 5;
    float4 accH[4], accT[4];
#pragma unroll
    for (int r = 0; r < 4; ++r) {
        accH[r] = make_float4(0.f, 0.f, 0.f, 0.f);
        accT[r] = make_float4(0.f, 0.f, 0.f, 0.f);
    }

    for (int k = 0; k < DIM; ++k) {
        float4 wh = *(const float4*)&WaTh[k][jc];
        float4 wt = *(const float4*)&WaTt[k][jc];
#pragma unroll
        for (int r = 0; r < 4; ++r) {
            float e = rows[rg * 4 + r][k];
            accH[r].x += e * wh.x; accH[r].y += e * wh.y;
            accH[r].z += e * wh.z; accH[r].w += e * wh.w;
            accT[r].x += e * wt.x; accT[r].y += e * wt.y;
            accT[r].z += e * wt.z; accT[r].w += e * wt.w;
        }
    }

#pragma unroll
    for (int r = 0; r < 4; ++r) {
        int grow = row0 + rg * 4 + r;
        if (grow < N_ENT) {
            *(float4*)&PH[(size_t)grow * DIM + jc] = accH[r];
            *(float4*)&PT[(size_t)grow * DIM + jc] = accT[r];
        }
    }
}

// ---------------------------------------------------------------------------
// K3: qh[i] = dot(PH[i], Wa2), qt[i] = dot(PT[i], Wa2)
__global__ __launch_bounds__(256) void k_q(const float* __restrict__ PH,
                                           const float* __restrict__ PT,
                                           const float* __restrict__ Wa2,
                                           float* __restrict__ qh,
                                           float* __restrict__ qt) {
    int idx = blockIdx.x * 256 + threadIdx.x;
    int i = idx >> 5, lane = idx & 31;
    if (i >= N_ENT) return;
    float4 w2 = *(const float4*)&Wa2[lane * 4];
    float4 a = *(const float4*)&PH[(size_t)i * DIM + lane * 4];
    float p = a.x * w2.x + a.y * w2.y + a.z * w2.z + a.w * w2.w;
#pragma unroll
    for (int m = 1; m <= 16; m <<= 1) p += __shfl_xor(p, m);
    if (lane == 0) qh[i] = p;
    float4 b = *(const float4*)&PT[(size_t)i * DIM + lane * 4];
    float q = b.x * w2.x + b.y * w2.y + b.z * w2.z + b.w * w2.w;
#pragma unroll
    for (int m = 1; m <= 16; m <<= 1) q += __shfl_xor(q, m);
    if (lane == 0) qt[i] = q;
}

// ---------------------------------------------------------------------------
// K4: deg[h]++ per edge (int atomics only)
__global__ __launch_bounds__(256) void k_count(const int* __restrict__ trip,
                                               int* __restrict__ deg) {
    int e = blockIdx.x * 256 + threadIdx.x;
    if (e < N_EDGES) atomicAdd(&deg[trip[e * 3]], 1);
}

// ---------------------------------------------------------------------------
// K5: single-block exclusive scan of deg -> off (and a scatter cursor copy)
__global__ __launch_bounds__(1024) void k_scan(const int* __restrict__ deg,
                                               int* __restrict__ off,
                                               int* __restrict__ cur) {
    __shared__ int s[1024];
    int t = threadIdx.x;
    const int CH = (N_ENT + 1023) / 1024;   // 98
    int base = t * CH;
    int lim = base + CH < N_ENT ? base + CH : N_ENT;
    int sum = 0;
    for (int i = base; i < lim; ++i) sum += deg[i];
    s[t] = sum;
    __syncthreads();
    for (int d = 1; d < 1024; d <<= 1) {
        int v = (t >= d) ? s[t - d] : 0;
        __syncthreads();
        s[t] += v;
        __syncthreads();
    }
    int run = s[t] - sum;                   // exclusive prefix
    for (int i = base; i < lim; ++i) {
        off[i] = run; cur[i] = run;
        run += deg[i];
    }
    if (t == 1023) off[N_ENT] = s[1023];
}

// ---------------------------------------------------------------------------
// K6: per edge: w = exp(leaky(qh+qr+qt+ba2)); CSR-scatter (r,t) packed + w
__global__ __launch_bounds__(256) void k_scatter(const int* __restrict__ trip,
                                                 const float* __restrict__ qh,
                                                 const float* __restrict__ qt,
                                                 const float* __restrict__ qr,
                                                 const float* __restrict__ ba2,
                                                 int* __restrict__ cur,
                                                 unsigned* __restrict__ pk,
                                                 float* __restrict__ warr) {
    int e = blockIdx.x * 256 + threadIdx.x;
    if (e >= N_EDGES) return;
    int h  = trip[e * 3 + 0];
    int tl = trip[e * 3 + 1];
    int r  = trip[e * 3 + 2];
    float b = qh[h] + qt[tl] + qr[r] + ba2[0];
    float lr = b > 0.f ? b : 0.01f * b;
    float w = expf(lr);
    int pos = atomicAdd(&cur[h], 1);
    pk[pos] = ((unsigned)r << 17) | (unsigned)tl;
    warr[pos] = w;
}

// ---------------------------------------------------------------------------
// K7: per head (32 lanes): acc = sum w*(PR[r]+PT[t]); sw = sum w;
//     out = elu((acc + sw*PH[h]) / sw')   -- no float atomics anywhere
__global__ __launch_bounds__(256) void k_gather(const int* __restrict__ off,
                                                const unsigned* __restrict__ pk,
                                                const float* __restrict__ warr,
                                                const float* __restrict__ PH,
                                                const float* __restrict__ PR,
                                                const float* __restrict__ PT,
                                                float* __restrict__ out) {
    int idx = blockIdx.x * 256 + threadIdx.x;
    int i = idx >> 5, lane = idx & 31;
    if (i >= N_ENT) return;
    int lane4 = lane * 4;
    int e0 = off[i], e1 = off[i + 1];
    float4 acc = make_float4(0.f, 0.f, 0.f, 0.f);
    float sw = 0.f;
    for (int e = e0; e < e1; ++e) {
        unsigned p = pk[e];
        float w = warr[e];
        int tt = (int)(p & 0x1FFFFu);
        int rr = (int)(p >> 17);
        float4 pr = *(const float4*)&PR[(size_t)rr * DIM + lane4];
        float4 pt = *(const float4*)&PT[(size_t)tt * DIM + lane4];
        acc.x += w * (pr.x + pt.x);
        acc.y += w * (pr.y + pt.y);
        acc.z += w * (pr.z + pt.z);
        acc.w += w * (pr.w + pt.w);
        sw += w;
    }
    float4 ph = *(const float4*)&PH[(size_t)i * DIM + lane4];
    acc.x += sw * ph.x; acc.y += sw * ph.y;
    acc.z += sw * ph.z; acc.w += sw * ph.w;
    float den = (sw == 0.f) ? 1e-12f : sw;
    float inv = 1.f / den;
    float vx = acc.x * inv, vy = acc.y * inv, vz = acc.z * inv, vw = acc.w * inv;
    vx = vx > 0.f ? vx : expm1f(vx);
    vy = vy > 0.f ? vy : expm1f(vy);
    vz = vz > 0.f ? vz : expm1f(vz);
    vw = vw > 0.f ? vw : expm1f(vw);
    *(float4*)&out[(size_t)i * DIM + lane4] = make_float4(vx, vy, vz, vw);
}

// ---------------------------------------------------------------------------
extern "C" void kernel_launch(void* const* d_in, const int* in_sizes, int n_in,
                              void* d_out, int out_size, void* d_ws, size_t ws_size,
                              hipStream_t stream) {
    const int*   trip = (const int*)d_in[0];
    const float* ent  = (const float*)d_in[1];
    const float* rel  = (const float*)d_in[2];
    const float* Wa   = (const float*)d_in[3];
    const float* ba   = (const float*)d_in[4];
    const float* Wa2  = (const float*)d_in[5];
    const float* ba2  = (const float*)d_in[6];
    float* out = (float*)d_out;

    float* ws = (float*)d_ws;
    size_t o = 0;
    float* PH = ws + o;        o += (size_t)N_ENT * DIM;     // 12.8M
    float* PT = ws + o;        o += (size_t)N_ENT * DIM;     // 12.8M
    float* PR = ws + o;        o += (size_t)N_REL * DIM;
    float* qh = ws + o;        o += N_ENT;
    float* qt = ws + o;        o += N_ENT;
    float* qr = ws + o;        o += N_REL;
    int*   deg = (int*)(ws + o);      o += N_ENT;
    int*   off = (int*)(ws + o);      o += N_ENT + 1;
    int*   cur = (int*)(ws + o);      o += N_ENT;
    unsigned* pk = (unsigned*)(ws + o); o += N_EDGES;
    float* warr = ws + o;      o += N_EDGES;

    hipMemsetAsync(deg, 0, (size_t)N_ENT * sizeof(int), stream);

    k_rel<<<N_REL, 128, 0, stream>>>(rel, Wa, ba, Wa2, PR, qr);
    k_ent<<<(N_ENT + 31) / 32, 256, 0, stream>>>(ent, Wa, PH, PT);
    k_q<<<(N_ENT * 32) / 256, 256, 0, stream>>>(PH, PT, Wa2, qh, qt);
    k_count<<<(N_EDGES + 255) / 256, 256, 0, stream>>>(trip, deg);
    k_scan<<<1, 1024, 0, stream>>>(deg, off, cur);
    k_scatter<<<(N_EDGES + 255) / 256, 256, 0, stream>>>(trip, qh, qt, qr, ba2, cur, pk, warr);
    k_gather<<<(N_ENT * 32) / 256, 256, 0, stream>>>(off, pk, warr, PH, PR, PT, out);
}

// Round 4
// 366.980 us; speedup vs baseline: 4.8371x; 2.0316x over previous
//
#include <hip/hip_runtime.h>

#define N_ENT   100000
#define N_REL   500
#define N_EDGES 800000
#define DIM     128
#define WA_LD   384

// scan config
#define SC_T 256
#define SC_C 2
#define SC_CHUNK (SC_T * SC_C)                      // 512
#define SC_B ((N_ENT + SC_CHUNK - 1) / SC_CHUNK)    // 196
#define DEG_PAD (SC_B * SC_CHUNK)                   // 100352

// ---------------------------------------------------------------------------
// K1: PR[r][j] = ba[j] + sum_k rel[r][k] * Wa[j][128+k]; qr[r] = dot(PR[r], Wa2)
__global__ __launch_bounds__(128) void k_rel(const float* __restrict__ rel,
                                             const float* __restrict__ Wa,
                                             const float* __restrict__ ba,
                                             const float* __restrict__ Wa2,
                                             float* __restrict__ PR,
                                             float* __restrict__ qr) {
    int r = blockIdx.x;
    int j = threadIdx.x;
    __shared__ float relrow[DIM];
    __shared__ float red[DIM];
    relrow[j] = rel[r * DIM + j];
    __syncthreads();
    const float* wrow = Wa + (size_t)j * WA_LD + 128;
    float acc = ba[j];
#pragma unroll 8
    for (int k = 0; k < DIM; ++k) acc += relrow[k] * wrow[k];
    PR[r * DIM + j] = acc;
    red[j] = acc * Wa2[j];
    __syncthreads();
    for (int s = 64; s > 0; s >>= 1) {
        if (j < s) red[j] += red[j + s];
        __syncthreads();
    }
    if (j == 0) qr[r] = red[0];
}

// ---------------------------------------------------------------------------
// K2: PH = ent @ Wa_h^T, PT = ent @ Wa_t^T, fused qh/qt = P·Wa2.
// 256 threads, 48 rows/block. Weights in LDS with XOR swizzle at float4
// granularity: group' = (j>>2) ^ (k&31)  -> staging writes 4-way (was 32-way),
// main-loop b128 reads conflict-free. rows padded [48][132] (528B = 33*16:
// float4-aligned, conflict-free b128 reads).
#define EROWS 48
__global__ __launch_bounds__(256) void k_ent(const float* __restrict__ ent,
                                             const float* __restrict__ Wa,
                                             const float* __restrict__ Wa2,
                                             float* __restrict__ PH,
                                             float* __restrict__ PT,
                                             float* __restrict__ qh,
                                             float* __restrict__ qt) {
    __shared__ float4 WH[DIM][32];      // 64 KB, swizzled
    __shared__ float4 WT[DIM][32];      // 64 KB, swizzled
    __shared__ float rows[EROWS][132];  // 24.75 KB
    int t = threadIdx.x;
    int row0 = blockIdx.x * EROWS;
    float* WHf = (float*)WH;
    float* WTf = (float*)WT;

    // stage weights (coalesced float4 global reads, swizzled scalar LDS writes)
#pragma unroll
    for (int it = 0; it < 16; ++it) {
        int idx = t + 256 * it;
        int j = idx >> 5;           // 0..127
        int k4 = idx & 31;          // float4 group along k
        float4 vh = *(const float4*)&Wa[(size_t)j * WA_LD + 4 * k4];
        float4 vt = *(const float4*)&Wa[(size_t)j * WA_LD + 256 + 4 * k4];
        int g = j >> 2, jl = j & 3;
#pragma unroll
        for (int q = 0; q < 4; ++q) {
            int k = 4 * k4 + q;
            int gp = g ^ (k & 31);
            float eh = q == 0 ? vh.x : q == 1 ? vh.y : q == 2 ? vh.z : vh.w;
            float et = q == 0 ? vt.x : q == 1 ? vt.y : q == 2 ? vt.z : vt.w;
            WHf[k * DIM + gp * 4 + jl] = eh;
            WTf[k * DIM + gp * 4 + jl] = et;
        }
    }
    // stage rows
#pragma unroll
    for (int it = 0; it < 6; ++it) {
        int idx = t + 256 * it;
        int rr = idx >> 5;
        int k4 = idx & 31;
        int grow = row0 + rr;
        float4 v = make_float4(0.f, 0.f, 0.f, 0.f);
        if (grow < N_ENT) v = *(const float4*)&ent[(size_t)grow * DIM + 4 * k4];
        *(float4*)&rows[rr][4 * k4] = v;
    }
    __syncthreads();

    int tc = t & 15, tr = t >> 4;
    int g0 = 2 * tc, g1 = 2 * tc + 1;
    float4 aH[3][2], aT[3][2];
#pragma unroll
    for (int rr = 0; rr < 3; ++rr)
#pragma unroll
        for (int g = 0; g < 2; ++g) {
            aH[rr][g] = make_float4(0.f, 0.f, 0.f, 0.f);
            aT[rr][g] = make_float4(0.f, 0.f, 0.f, 0.f);
        }

    for (int kb = 0; kb < 32; ++kb) {
        float4 rv[3];
#pragma unroll
        for (int rr = 0; rr < 3; ++rr)
            rv[rr] = *(const float4*)&rows[tr * 3 + rr][4 * kb];
#pragma unroll
        for (int q = 0; q < 4; ++q) {
            int k = 4 * kb + q;
            int m = k & 31;
            float4 wh0 = WH[k][g0 ^ m], wh1 = WH[k][g1 ^ m];
            float4 wt0 = WT[k][g0 ^ m], wt1 = WT[k][g1 ^ m];
#pragma unroll
            for (int rr = 0; rr < 3; ++rr) {
                float e = q == 0 ? rv[rr].x : q == 1 ? rv[rr].y
                        : q == 2 ? rv[rr].z : rv[rr].w;
                aH[rr][0].x += e * wh0.x; aH[rr][0].y += e * wh0.y;
                aH[rr][0].z += e * wh0.z; aH[rr][0].w += e * wh0.w;
                aH[rr][1].x += e * wh1.x; aH[rr][1].y += e * wh1.y;
                aH[rr][1].z += e * wh1.z; aH[rr][1].w += e * wh1.w;
                aT[rr][0].x += e * wt0.x; aT[rr][0].y += e * wt0.y;
                aT[rr][0].z += e * wt0.z; aT[rr][0].w += e * wt0.w;
                aT[rr][1].x += e * wt1.x; aT[rr][1].y += e * wt1.y;
                aT[rr][1].z += e * wt1.z; aT[rr][1].w += e * wt1.w;
            }
        }
    }

    // epilogue: store PH/PT + fused q = P . Wa2 (reduce over 16 col-lanes)
    float4 w2a = *(const float4*)&Wa2[8 * tc];
    float4 w2b = *(const float4*)&Wa2[8 * tc + 4];
#pragma unroll
    for (int rr = 0; rr < 3; ++rr) {
        int grow = row0 + tr * 3 + rr;
        float qhp = aH[rr][0].x * w2a.x + aH[rr][0].y * w2a.y
                  + aH[rr][0].z * w2a.z + aH[rr][0].w * w2a.w
                  + aH[rr][1].x * w2b.x + aH[rr][1].y * w2b.y
                  + aH[rr][1].z * w2b.z + aH[rr][1].w * w2b.w;
        float qtp = aT[rr][0].x * w2a.x + aT[rr][0].y * w2a.y
                  + aT[rr][0].z * w2a.z + aT[rr][0].w * w2a.w
                  + aT[rr][1].x * w2b.x + aT[rr][1].y * w2b.y
                  + aT[rr][1].z * w2b.z + aT[rr][1].w * w2b.w;
#pragma unroll
        for (int m = 1; m <= 8; m <<= 1) {
            qhp += __shfl_xor(qhp, m);
            qtp += __shfl_xor(qtp, m);
        }
        if (grow < N_ENT) {
            *(float4*)&PH[(size_t)grow * DIM + 8 * tc]     = aH[rr][0];
            *(float4*)&PH[(size_t)grow * DIM + 8 * tc + 4] = aH[rr][1];
            *(float4*)&PT[(size_t)grow * DIM + 8 * tc]     = aT[rr][0];
            *(float4*)&PT[(size_t)grow * DIM + 8 * tc + 4] = aT[rr][1];
            if (tc == 0) { qh[grow] = qhp; qt[grow] = qtp; }
        }
    }
}

// ---------------------------------------------------------------------------
// K3: deg[h]++ per edge
__global__ __launch_bounds__(256) void k_count(const int* __restrict__ trip,
                                               int* __restrict__ deg) {
    int e = blockIdx.x * 256 + threadIdx.x;
    if (e < N_EDGES) atomicAdd(&deg[trip[e * 3]], 1);
}

// ---------------------------------------------------------------------------
// scan: block partial sums
__global__ __launch_bounds__(SC_T) void k_scan1(const int* __restrict__ deg,
                                                int* __restrict__ partial) {
    int b = blockIdx.x, t = threadIdx.x;
    int i0 = b * SC_CHUNK + t * SC_C;
    int s = deg[i0] + deg[i0 + 1];
#pragma unroll
    for (int m = 1; m <= 32; m <<= 1) s += __shfl_xor(s, m);
    __shared__ int ws_[SC_T / 64];
    int lane = t & 63, wid = t >> 6;
    if (lane == 0) ws_[wid] = s;
    __syncthreads();
    if (t == 0) {
        int tot = 0;
        for (int w = 0; w < SC_T / 64; ++w) tot += ws_[w];
        partial[b] = tot;
    }
}

// scan of block partials (1 block)
__global__ __launch_bounds__(SC_T) void k_scan2(const int* __restrict__ partial,
                                                int* __restrict__ base,
                                                int* __restrict__ off) {
    __shared__ int s[SC_T];
    int t = threadIdx.x;
    int v = (t < SC_B) ? partial[t] : 0;
    s[t] = v;
    __syncthreads();
    for (int d = 1; d < SC_T; d <<= 1) {
        int u = (t >= d) ? s[t - d] : 0;
        __syncthreads();
        s[t] += u;
        __syncthreads();
    }
    if (t < SC_B) base[t] = s[t] - v;
    if (t == SC_T - 1) off[N_ENT] = s[t];
}

// per-block rescan -> off, cur
__global__ __launch_bounds__(SC_T) void k_scan3(const int* __restrict__ deg,
                                                const int* __restrict__ base,
                                                int* __restrict__ off,
                                                int* __restrict__ cur) {
    __shared__ int s[SC_T];
    int b = blockIdx.x, t = threadIdx.x;
    int i0 = b * SC_CHUNK + t * SC_C;
    int d0 = deg[i0], d1 = deg[i0 + 1];
    int tsum = d0 + d1;
    s[t] = tsum;
    __syncthreads();
    for (int d = 1; d < SC_T; d <<= 1) {
        int u = (t >= d) ? s[t - d] : 0;
        __syncthreads();
        s[t] += u;
        __syncthreads();
    }
    int excl = s[t] - tsum + base[b];
    if (i0 < N_ENT)     { off[i0] = excl;          cur[i0] = excl; }
    if (i0 + 1 < N_ENT) { off[i0 + 1] = excl + d0; cur[i0 + 1] = excl + d0; }
}

// ---------------------------------------------------------------------------
// K6: per edge: w = exp(leaky(qh+qr+qt+ba2)); CSR-scatter packed (r,t) + w as float2
__global__ __launch_bounds__(256) void k_scatter(const int* __restrict__ trip,
                                                 const float* __restrict__ qh,
                                                 const float* __restrict__ qt,
                                                 const float* __restrict__ qr,
                                                 const float* __restrict__ ba2,
                                                 int* __restrict__ cur,
                                                 float2* __restrict__ pkw) {
    int e = blockIdx.x * 256 + threadIdx.x;
    if (e >= N_EDGES) return;
    int h  = trip[e * 3 + 0];
    int tl = trip[e * 3 + 1];
    int r  = trip[e * 3 + 2];
    float b = qh[h] + qt[tl] + qr[r] + ba2[0];
    float lr = b > 0.f ? b : 0.01f * b;
    float w = expf(lr);
    int pos = atomicAdd(&cur[h], 1);
    float2 v;
    v.x = __uint_as_float(((unsigned)r << 17) | (unsigned)tl);
    v.y = w;
    pkw[pos] = v;
}

// ---------------------------------------------------------------------------
// K7: per head (32 lanes): acc = sum w*(PR[r]+PT[t]); out = elu((acc+sw*PH[h])/sw')
__global__ __launch_bounds__(256) void k_gather(const int* __restrict__ off,
                                                const float2* __restrict__ pkw,
                                                const float* __restrict__ PH,
                                                const float* __restrict__ PR,
                                                const float* __restrict__ PT,
                                                float* __restrict__ out) {
    int idx = blockIdx.x * 256 + threadIdx.x;
    int i = idx >> 5, lane = idx & 31;
    if (i >= N_ENT) return;
    int lane4 = lane * 4;
    int e0 = off[i], e1 = off[i + 1];
    float4 acc = make_float4(0.f, 0.f, 0.f, 0.f);
    float sw = 0.f;
    for (int e = e0; e < e1; ++e) {
        float2 pw = pkw[e];
        unsigned p = __float_as_uint(pw.x);
        float w = pw.y;
        int tt = (int)(p & 0x1FFFFu);
        int rr = (int)(p >> 17);
        float4 pr = *(const float4*)&PR[(size_t)rr * DIM + lane4];
        float4 pt = *(const float4*)&PT[(size_t)tt * DIM + lane4];
        acc.x += w * (pr.x + pt.x);
        acc.y += w * (pr.y + pt.y);
        acc.z += w * (pr.z + pt.z);
        acc.w += w * (pr.w + pt.w);
        sw += w;
    }
    float4 ph = *(const float4*)&PH[(size_t)i * DIM + lane4];
    acc.x += sw * ph.x; acc.y += sw * ph.y;
    acc.z += sw * ph.z; acc.w += sw * ph.w;
    float den = (sw == 0.f) ? 1e-12f : sw;
    float inv = 1.f / den;
    float vx = acc.x * inv, vy = acc.y * inv, vz = acc.z * inv, vw = acc.w * inv;
    vx = vx > 0.f ? vx : expm1f(vx);
    vy = vy > 0.f ? vy : expm1f(vy);
    vz = vz > 0.f ? vz : expm1f(vz);
    vw = vw > 0.f ? vw : expm1f(vw);
    *(float4*)&out[(size_t)i * DIM + lane4] = make_float4(vx, vy, vz, vw);
}

// ---------------------------------------------------------------------------
extern "C" void kernel_launch(void* const* d_in, const int* in_sizes, int n_in,
                              void* d_out, int out_size, void* d_ws, size_t ws_size,
                              hipStream_t stream) {
    const int*   trip = (const int*)d_in[0];
    const float* ent  = (const float*)d_in[1];
    const float* rel  = (const float*)d_in[2];
    const float* Wa   = (const float*)d_in[3];
    const float* ba   = (const float*)d_in[4];
    const float* Wa2  = (const float*)d_in[5];
    const float* ba2  = (const float*)d_in[6];
    float* out = (float*)d_out;

    float* ws = (float*)d_ws;
    size_t o = 0;
    float* PH = ws + o;        o += (size_t)N_ENT * DIM;
    float* PT = ws + o;        o += (size_t)N_ENT * DIM;
    float* PR = ws + o;        o += (size_t)N_REL * DIM;
    float* qh = ws + o;        o += N_ENT;
    float* qt = ws + o;        o += N_ENT;
    float* qr = ws + o;        o += N_REL + 3;          // keep alignment even
    int*   deg = (int*)(ws + o);      o += DEG_PAD;
    int*   off = (int*)(ws + o);      o += N_ENT + 1;
    int*   cur = (int*)(ws + o);      o += N_ENT + 1;
    int*   partial = (int*)(ws + o);  o += SC_T;
    int*   base = (int*)(ws + o);     o += SC_T;
    float2* pkw = (float2*)(ws + o);  o += (size_t)N_EDGES * 2;

    hipMemsetAsync(deg, 0, (size_t)DEG_PAD * sizeof(int), stream);

    k_rel<<<N_REL, 128, 0, stream>>>(rel, Wa, ba, Wa2, PR, qr);
    k_ent<<<(N_ENT + EROWS - 1) / EROWS, 256, 0, stream>>>(ent, Wa, Wa2, PH, PT, qh, qt);
    k_count<<<(N_EDGES + 255) / 256, 256, 0, stream>>>(trip, deg);
    k_scan1<<<SC_B, SC_T, 0, stream>>>(deg, partial);
    k_scan2<<<1, SC_T, 0, stream>>>(partial, base, off);
    k_scan3<<<SC_B, SC_T, 0, stream>>>(deg, base, off, cur);
    k_scatter<<<(N_EDGES + 255) / 256, 256, 0, stream>>>(trip, qh, qt, qr, ba2, cur, pkw);
    k_gather<<<(N_ENT * 32) / 256, 256, 0, stream>>>(off, pkw, PH, PR, PT, out);
}

// Round 6
// 248.551 us; speedup vs baseline: 7.1418x; 1.4765x over previous
//
#include <hip/hip_runtime.h>

#define N_ENT   100000
#define N_REL   500
#define N_EDGES 800000
#define DIM     128
#define WA_LD   384

// scan config
#define SC_T 256
#define SC_C 2
#define SC_CHUNK (SC_T * SC_C)                      // 512
#define SC_B ((N_ENT + SC_CHUNK - 1) / SC_CHUNK)    // 196
#define DEG_PAD (SC_B * SC_CHUNK)                   // 100352

typedef __attribute__((ext_vector_type(8))) short  s8v;   // 8 bf16 (4 VGPR)
typedef __attribute__((ext_vector_type(4))) float  f4v;   // MFMA acc

__device__ __forceinline__ unsigned short f2bf(float x) {
    unsigned u = __float_as_uint(x);
    return (unsigned short)((u + 0x7FFFu + ((u >> 16) & 1u)) >> 16);
}
__device__ __forceinline__ float bf2f(unsigned short h) {
    return __uint_as_float(((unsigned)h) << 16);
}

// ---------------------------------------------------------------------------
// K1: PR[r][j] = ba[j] + sum_k rel[r][k] * Wa[j][128+k]; qr[r] = dot(PR[r], Wa2)
__global__ __launch_bounds__(128) void k_rel(const float* __restrict__ rel,
                                             const float* __restrict__ Wa,
                                             const float* __restrict__ ba,
                                             const float* __restrict__ Wa2,
                                             float* __restrict__ PR,
                                             float* __restrict__ qr) {
    int r = blockIdx.x;
    int j = threadIdx.x;
    __shared__ float relrow[DIM];
    __shared__ float red[DIM];
    relrow[j] = rel[r * DIM + j];
    __syncthreads();
    const float* wrow = Wa + (size_t)j * WA_LD + 128;
    float acc = ba[j];
#pragma unroll 8
    for (int k = 0; k < DIM; ++k) acc += relrow[k] * wrow[k];
    PR[r * DIM + j] = acc;
    red[j] = acc * Wa2[j];
    __syncthreads();
    for (int s = 64; s > 0; s >>= 1) {
        if (j < s) red[j] += red[j + s];
        __syncthreads();
    }
    if (j == 0) qr[r] = red[0];
}

// ---------------------------------------------------------------------------
// K2 (MFMA): C[100000x256] = ent[100000x128] @ [Wh | Wt]  (fp32 via bf16 split:
// AhBh + AhBl + AlBh, error ~2^-16 rel). Weights staged once/block into LDS in
// exact B-fragment order (lane-contiguous 16B -> conflict-free ds_read_b128).
// Per block: 128 rows; 4 waves x 32 rows (2x 16-row subtiles).
// Fragment layouts (m89-verified convention, 16x16x32 bf16):
//   A: lane l holds A[l&15][kc*32 + (l>>4)*8 + e]
//   B: lane l holds B[kc*32 + (l>>4)*8 + e][l&15 (+16*nt)]
//   D: lane l, reg g holds C[(l>>4)*4 + g][l&15 (+16*nt)]
#define MT 128
__global__ __launch_bounds__(256, 1) void k_ent_mfma(const float* __restrict__ ent,
                                                     const float* __restrict__ Wa,
                                                     const float* __restrict__ Wa2,
                                                     float* __restrict__ PH,
                                                     float* __restrict__ PT,
                                                     float* __restrict__ qh,
                                                     float* __restrict__ qt) {
    __shared__ short B2[2][32768];   // [hi/lo][ ((kc*16+nt)*64 + lane)*8 + e ] : 128 KB
    int t = threadIdx.x;

    // ---- stage weights once per block (reads L2-resident Wa) ----
#pragma unroll
    for (int tt = 0; tt < 2; ++tt) {
#pragma unroll
        for (int it = 0; it < 8; ++it) {
            int g = t + 256 * it;        // granule 0..2047: 8 consecutive k of col j
            int j = g >> 4;              // 0..127 (output col within table)
            int k8 = g & 15;             // which 8-float k-granule
            const float* src = Wa + (size_t)j * WA_LD + tt * 256 + k8 * 8;
            float4 v0 = *(const float4*)src;
            float4 v1 = *(const float4*)(src + 4);
            float x[8] = {v0.x, v0.y, v0.z, v0.w, v1.x, v1.y, v1.z, v1.w};
            s8v hv, lv;
#pragma unroll
            for (int e = 0; e < 8; ++e) {
                unsigned short hb = f2bf(x[e]);
                hv[e] = (short)hb;
                lv[e] = (short)f2bf(x[e] - bf2f(hb));
            }
            int col = tt * 128 + j;
            int kc = k8 >> 2;
            int lanep = (k8 & 3) * 16 + (col & 15);
            int nt = col >> 4;
            size_t base = ((size_t)((kc * 16 + nt) * 64 + lanep)) * 8;
            *(s8v*)&B2[0][base] = hv;
            *(s8v*)&B2[1][base] = lv;
        }
    }

    int wv = t >> 6;                 // wave 0..3
    int lane = t & 63;
    int l15 = lane & 15, lg = lane >> 4;
    int m0 = blockIdx.x * MT + wv * 32;

    f4v acc[2][16];
#pragma unroll
    for (int s = 0; s < 2; ++s)
#pragma unroll
        for (int nt = 0; nt < 16; ++nt)
            acc[s][nt] = (f4v){0.f, 0.f, 0.f, 0.f};

    __syncthreads();

#pragma unroll
    for (int kc = 0; kc < 4; ++kc) {
        s8v Ah[2], Al[2];
#pragma unroll
        for (int s = 0; s < 2; ++s) {
            int row = m0 + s * 16 + l15;
            if (row < N_ENT) {
                const float* ap = ent + (size_t)row * DIM + kc * 32 + lg * 8;
                float4 v0 = *(const float4*)ap;
                float4 v1 = *(const float4*)(ap + 4);
                float x[8] = {v0.x, v0.y, v0.z, v0.w, v1.x, v1.y, v1.z, v1.w};
#pragma unroll
                for (int e = 0; e < 8; ++e) {
                    unsigned short hb = f2bf(x[e]);
                    Ah[s][e] = (short)hb;
                    Al[s][e] = (short)f2bf(x[e] - bf2f(hb));
                }
            } else {
                Ah[s] = (s8v){0, 0, 0, 0, 0, 0, 0, 0};
                Al[s] = (s8v){0, 0, 0, 0, 0, 0, 0, 0};
            }
        }
#pragma unroll
        for (int nt = 0; nt < 16; ++nt) {
            size_t bb = ((size_t)((kc * 16 + nt) * 64 + lane)) * 8;
            s8v bh = *(const s8v*)&B2[0][bb];
            s8v bl = *(const s8v*)&B2[1][bb];
#pragma unroll
            for (int s = 0; s < 2; ++s) {
                acc[s][nt] = __builtin_amdgcn_mfma_f32_16x16x32_bf16(Ah[s], bh, acc[s][nt], 0, 0, 0);
                acc[s][nt] = __builtin_amdgcn_mfma_f32_16x16x32_bf16(Al[s], bh, acc[s][nt], 0, 0, 0);
                acc[s][nt] = __builtin_amdgcn_mfma_f32_16x16x32_bf16(Ah[s], bl, acc[s][nt], 0, 0, 0);
            }
        }
    }

    // ---- epilogue: store PH/PT + fused qh/qt = P . Wa2 ----
    // Wa2 has 128 elements; tile nt (0..15) maps to Wa2 column (nt&7)*16+l15
    // for BOTH tables (bug fixed: was Wa2[nt*16+l15] -> OOB for nt>=8).
    float wa2v[8];
#pragma unroll
    for (int c8 = 0; c8 < 8; ++c8) wa2v[c8] = Wa2[c8 * 16 + l15];

#pragma unroll
    for (int s = 0; s < 2; ++s) {
        int rowb = m0 + s * 16 + lg * 4;
        float qhp[4] = {0.f, 0.f, 0.f, 0.f};
        float qtp[4] = {0.f, 0.f, 0.f, 0.f};
#pragma unroll
        for (int nt = 0; nt < 16; ++nt) {
#pragma unroll
            for (int g = 0; g < 4; ++g) {
                float v = acc[s][nt][g];
                if (nt < 8) qhp[g] += v * wa2v[nt];
                else        qtp[g] += v * wa2v[nt & 7];
                int row = rowb + g;
                if (row < N_ENT) {
                    if (nt < 8) PH[(size_t)row * DIM + nt * 16 + l15] = v;
                    else        PT[(size_t)row * DIM + (nt - 8) * 16 + l15] = v;
                }
            }
        }
#pragma unroll
        for (int g = 0; g < 4; ++g) {
            float a = qhp[g], b = qtp[g];
#pragma unroll
            for (int m = 1; m <= 8; m <<= 1) {
                a += __shfl_xor(a, m);
                b += __shfl_xor(b, m);
            }
            int row = rowb + g;
            if (l15 == 0 && row < N_ENT) { qh[row] = a; qt[row] = b; }
        }
    }
}

// ---------------------------------------------------------------------------
// K3: deg[h]++ per edge
__global__ __launch_bounds__(256) void k_count(const int* __restrict__ trip,
                                               int* __restrict__ deg) {
    int e = blockIdx.x * 256 + threadIdx.x;
    if (e < N_EDGES) atomicAdd(&deg[trip[e * 3]], 1);
}

// ---------------------------------------------------------------------------
// scan: block partial sums
__global__ __launch_bounds__(SC_T) void k_scan1(const int* __restrict__ deg,
                                                int* __restrict__ partial) {
    int b = blockIdx.x, t = threadIdx.x;
    int i0 = b * SC_CHUNK + t * SC_C;
    int s = deg[i0] + deg[i0 + 1];
#pragma unroll
    for (int m = 1; m <= 32; m <<= 1) s += __shfl_xor(s, m);
    __shared__ int ws_[SC_T / 64];
    int lane = t & 63, wid = t >> 6;
    if (lane == 0) ws_[wid] = s;
    __syncthreads();
    if (t == 0) {
        int tot = 0;
        for (int w = 0; w < SC_T / 64; ++w) tot += ws_[w];
        partial[b] = tot;
    }
}

// scan of block partials (1 block)
__global__ __launch_bounds__(SC_T) void k_scan2(const int* __restrict__ partial,
                                                int* __restrict__ base,
                                                int* __restrict__ off) {
    __shared__ int s[SC_T];
    int t = threadIdx.x;
    int v = (t < SC_B) ? partial[t] : 0;
    s[t] = v;
    __syncthreads();
    for (int d = 1; d < SC_T; d <<= 1) {
        int u = (t >= d) ? s[t - d] : 0;
        __syncthreads();
        s[t] += u;
        __syncthreads();
    }
    if (t < SC_B) base[t] = s[t] - v;
    if (t == SC_T - 1) off[N_ENT] = s[t];
}

// per-block rescan -> off, cur
__global__ __launch_bounds__(SC_T) void k_scan3(const int* __restrict__ deg,
                                                const int* __restrict__ base,
                                                int* __restrict__ off,
                                                int* __restrict__ cur) {
    __shared__ int s[SC_T];
    int b = blockIdx.x, t = threadIdx.x;
    int i0 = b * SC_CHUNK + t * SC_C;
    int d0 = deg[i0], d1 = deg[i0 + 1];
    int tsum = d0 + d1;
    s[t] = tsum;
    __syncthreads();
    for (int d = 1; d < SC_T; d <<= 1) {
        int u = (t >= d) ? s[t - d] : 0;
        __syncthreads();
        s[t] += u;
        __syncthreads();
    }
    int excl = s[t] - tsum + base[b];
    if (i0 < N_ENT)     { off[i0] = excl;          cur[i0] = excl; }
    if (i0 + 1 < N_ENT) { off[i0 + 1] = excl + d0; cur[i0 + 1] = excl + d0; }
}

// ---------------------------------------------------------------------------
// K6: per edge: w = exp(leaky(qh+qr+qt+ba2)); CSR-scatter packed (r,t) + w as float2
__global__ __launch_bounds__(256) void k_scatter(const int* __restrict__ trip,
                                                 const float* __restrict__ qh,
                                                 const float* __restrict__ qt,
                                                 const float* __restrict__ qr,
                                                 const float* __restrict__ ba2,
                                                 int* __restrict__ cur,
                                                 float2* __restrict__ pkw) {
    int e = blockIdx.x * 256 + threadIdx.x;
    if (e >= N_EDGES) return;
    int h  = trip[e * 3 + 0];
    int tl = trip[e * 3 + 1];
    int r  = trip[e * 3 + 2];
    float b = qh[h] + qt[tl] + qr[r] + ba2[0];
    float lr = b > 0.f ? b : 0.01f * b;
    float w = expf(lr);
    int pos = atomicAdd(&cur[h], 1);
    float2 v;
    v.x = __uint_as_float(((unsigned)r << 17) | (unsigned)tl);
    v.y = w;
    pkw[pos] = v;
}

// ---------------------------------------------------------------------------
// K7: per head (32 lanes): acc = sum w*(PR[r]+PT[t]); out = elu((acc+sw*PH[h])/sw')
__global__ __launch_bounds__(256) void k_gather(const int* __restrict__ off,
                                                const float2* __restrict__ pkw,
                                                const float* __restrict__ PH,
                                                const float* __restrict__ PR,
                                                const float* __restrict__ PT,
                                                float* __restrict__ out) {
    int idx = blockIdx.x * 256 + threadIdx.x;
    int i = idx >> 5, lane = idx & 31;
    if (i >= N_ENT) return;
    int lane4 = lane * 4;
    int e0 = off[i], e1 = off[i + 1];
    float4 acc = make_float4(0.f, 0.f, 0.f, 0.f);
    float sw = 0.f;
    for (int e = e0; e < e1; ++e) {
        float2 pw = pkw[e];
        unsigned p = __float_as_uint(pw.x);
        float w = pw.y;
        int tt = (int)(p & 0x1FFFFu);
        int rr = (int)(p >> 17);
        float4 pr = *(const float4*)&PR[(size_t)rr * DIM + lane4];
        float4 pt = *(const float4*)&PT[(size_t)tt * DIM + lane4];
        acc.x += w * (pr.x + pt.x);
        acc.y += w * (pr.y + pt.y);
        acc.z += w * (pr.z + pt.z);
        acc.w += w * (pr.w + pt.w);
        sw += w;
    }
    float4 ph = *(const float4*)&PH[(size_t)i * DIM + lane4];
    acc.x += sw * ph.x; acc.y += sw * ph.y;
    acc.z += sw * ph.z; acc.w += sw * ph.w;
    float den = (sw == 0.f) ? 1e-12f : sw;
    float inv = 1.f / den;
    float vx = acc.x * inv, vy = acc.y * inv, vz = acc.z * inv, vw = acc.w * inv;
    vx = vx > 0.f ? vx : expm1f(vx);
    vy = vy > 0.f ? vy : expm1f(vy);
    vz = vz > 0.f ? vz : expm1f(vz);
    vw = vw > 0.f ? vw : expm1f(vw);
    *(float4*)&out[(size_t)i * DIM + lane4] = make_float4(vx, vy, vz, vw);
}

// ---------------------------------------------------------------------------
extern "C" void kernel_launch(void* const* d_in, const int* in_sizes, int n_in,
                              void* d_out, int out_size, void* d_ws, size_t ws_size,
                              hipStream_t stream) {
    const int*   trip = (const int*)d_in[0];
    const float* ent  = (const float*)d_in[1];
    const float* rel  = (const float*)d_in[2];
    const float* Wa   = (const float*)d_in[3];
    const float* ba   = (const float*)d_in[4];
    const float* Wa2  = (const float*)d_in[5];
    const float* ba2  = (const float*)d_in[6];
    float* out = (float*)d_out;

    float* ws = (float*)d_ws;
    size_t o = 0;
    float* PH = ws + o;        o += (size_t)N_ENT * DIM;
    float* PT = ws + o;        o += (size_t)N_ENT * DIM;
    float* PR = ws + o;        o += (size_t)N_REL * DIM;
    float* qh = ws + o;        o += N_ENT;
    float* qt = ws + o;        o += N_ENT;
    float* qr = ws + o;        o += N_REL + 3;          // keep alignment even
    int*   deg = (int*)(ws + o);      o += DEG_PAD;
    int*   off = (int*)(ws + o);      o += N_ENT + 1;
    int*   cur = (int*)(ws + o);      o += N_ENT + 1;
    int*   partial = (int*)(ws + o);  o += SC_T;
    int*   base = (int*)(ws + o);     o += SC_T;
    float2* pkw = (float2*)(ws + o);  o += (size_t)N_EDGES * 2;

    hipMemsetAsync(deg, 0, (size_t)DEG_PAD * sizeof(int), stream);

    k_rel<<<N_REL, 128, 0, stream>>>(rel, Wa, ba, Wa2, PR, qr);
    k_ent_mfma<<<(N_ENT + MT - 1) / MT, 256, 0, stream>>>(ent, Wa, Wa2, PH, PT, qh, qt);
    k_count<<<(N_EDGES + 255) / 256, 256, 0, stream>>>(trip, deg);
    k_scan1<<<SC_B, SC_T, 0, stream>>>(deg, partial);
    k_scan2<<<1, SC_T, 0, stream>>>(partial, base, off);
    k_scan3<<<SC_B, SC_T, 0, stream>>>(deg, base, off, cur);
    k_scatter<<<(N_EDGES + 255) / 256, 256, 0, stream>>>(trip, qh, qt, qr, ba2, cur, pkw);
    k_gather<<<(N_ENT * 32) / 256, 256, 0, stream>>>(off, pkw, PH, PR, PT, out);
}

// Round 7
// 223.557 us; speedup vs baseline: 7.9403x; 1.1118x over previous
//
#include <hip/hip_runtime.h>

#define N_ENT   100000
#define N_REL   500
#define N_EDGES 800000
#define DIM     128
#define WA_LD   384

// scan config
#define SC_T 256
#define SC_C 2
#define SC_CHUNK (SC_T * SC_C)                      // 512
#define SC_B ((N_ENT + SC_CHUNK - 1) / SC_CHUNK)    // 196
#define DEG_PAD (SC_B * SC_CHUNK)                   // 100352

typedef __attribute__((ext_vector_type(8))) short  s8v;   // 8 bf16 (4 VGPR)
typedef __attribute__((ext_vector_type(4))) float  f4v;   // MFMA acc

__device__ __forceinline__ unsigned short f2bf(float x) {
    unsigned u = __float_as_uint(x);
    return (unsigned short)((u + 0x7FFFu + ((u >> 16) & 1u)) >> 16);
}
__device__ __forceinline__ float bf2f(unsigned short h) {
    return __uint_as_float(((unsigned)h) << 16);
}

// ---------------------------------------------------------------------------
// K1: PR[r][j] = ba[j] + sum_k rel[r][k] * Wa[j][128+k]; qr[r] = dot(PR[r], Wa2)
__global__ __launch_bounds__(128) void k_rel(const float* __restrict__ rel,
                                             const float* __restrict__ Wa,
                                             const float* __restrict__ ba,
                                             const float* __restrict__ Wa2,
                                             float* __restrict__ PR,
                                             float* __restrict__ qr) {
    int r = blockIdx.x;
    int j = threadIdx.x;
    __shared__ float relrow[DIM];
    __shared__ float red[DIM];
    relrow[j] = rel[r * DIM + j];
    __syncthreads();
    const float* wrow = Wa + (size_t)j * WA_LD + 128;
    float acc = ba[j];
#pragma unroll 8
    for (int k = 0; k < DIM; ++k) acc += relrow[k] * wrow[k];
    PR[r * DIM + j] = acc;
    red[j] = acc * Wa2[j];
    __syncthreads();
    for (int s = 64; s > 0; s >>= 1) {
        if (j < s) red[j] += red[j + s];
        __syncthreads();
    }
    if (j == 0) qr[r] = red[0];
}

// ---------------------------------------------------------------------------
// K2 (MFMA): C[100000x256] = ent[100000x128] @ [Wh | Wt]  (fp32 via bf16 split:
// AhBh + AhBl + AlBh). Weights staged once/block in LDS in exact B-fragment
// order (lane-contiguous 16B -> conflict-free ds_read_b128).
// Round 6 fix: 512 threads / 8 waves (2 waves/SIMD) x 32 rows = MT 256 rows
// per block -- was 4 waves (1/SIMD, latency-bound at MfmaUtil 9%).
// Fragment layouts (m89-verified convention, 16x16x32 bf16):
//   A: lane l holds A[l&15][kc*32 + (l>>4)*8 + e]
//   B: lane l holds B[kc*32 + (l>>4)*8 + e][l&15 (+16*nt)]
//   D: lane l, reg g holds C[(l>>4)*4 + g][l&15 (+16*nt)]
#define MT 256
__global__ __launch_bounds__(512, 1) void k_ent_mfma(const float* __restrict__ ent,
                                                     const float* __restrict__ Wa,
                                                     const float* __restrict__ Wa2,
                                                     float* __restrict__ PH,
                                                     float* __restrict__ PT,
                                                     float* __restrict__ qh,
                                                     float* __restrict__ qt) {
    __shared__ short B2[2][32768];   // [hi/lo][ ((kc*16+nt)*64 + lane)*8 + e ] : 128 KB
    int t = threadIdx.x;

    // ---- stage weights once per block (reads L2-resident Wa) ----
#pragma unroll
    for (int tt = 0; tt < 2; ++tt) {
#pragma unroll
        for (int it = 0; it < 4; ++it) {
            int g = t + 512 * it;        // granule 0..2047: 8 consecutive k of col j
            int j = g >> 4;              // 0..127 (output col within table)
            int k8 = g & 15;             // which 8-float k-granule
            const float* src = Wa + (size_t)j * WA_LD + tt * 256 + k8 * 8;
            float4 v0 = *(const float4*)src;
            float4 v1 = *(const float4*)(src + 4);
            float x[8] = {v0.x, v0.y, v0.z, v0.w, v1.x, v1.y, v1.z, v1.w};
            s8v hv, lv;
#pragma unroll
            for (int e = 0; e < 8; ++e) {
                unsigned short hb = f2bf(x[e]);
                hv[e] = (short)hb;
                lv[e] = (short)f2bf(x[e] - bf2f(hb));
            }
            int col = tt * 128 + j;
            int kc = k8 >> 2;
            int lanep = (k8 & 3) * 16 + (col & 15);
            int nt = col >> 4;
            size_t base = ((size_t)((kc * 16 + nt) * 64 + lanep)) * 8;
            *(s8v*)&B2[0][base] = hv;
            *(s8v*)&B2[1][base] = lv;
        }
    }

    int wv = t >> 6;                 // wave 0..7
    int lane = t & 63;
    int l15 = lane & 15, lg = lane >> 4;
    int m0 = blockIdx.x * MT + wv * 32;

    f4v acc[2][16];
#pragma unroll
    for (int s = 0; s < 2; ++s)
#pragma unroll
        for (int nt = 0; nt < 16; ++nt)
            acc[s][nt] = (f4v){0.f, 0.f, 0.f, 0.f};

    __syncthreads();

#pragma unroll
    for (int kc = 0; kc < 4; ++kc) {
        s8v Ah[2], Al[2];
#pragma unroll
        for (int s = 0; s < 2; ++s) {
            int row = m0 + s * 16 + l15;
            if (row < N_ENT) {
                const float* ap = ent + (size_t)row * DIM + kc * 32 + lg * 8;
                float4 v0 = *(const float4*)ap;
                float4 v1 = *(const float4*)(ap + 4);
                float x[8] = {v0.x, v0.y, v0.z, v0.w, v1.x, v1.y, v1.z, v1.w};
#pragma unroll
                for (int e = 0; e < 8; ++e) {
                    unsigned short hb = f2bf(x[e]);
                    Ah[s][e] = (short)hb;
                    Al[s][e] = (short)f2bf(x[e] - bf2f(hb));
                }
            } else {
                Ah[s] = (s8v){0, 0, 0, 0, 0, 0, 0, 0};
                Al[s] = (s8v){0, 0, 0, 0, 0, 0, 0, 0};
            }
        }
#pragma unroll
        for (int nt = 0; nt < 16; ++nt) {
            size_t bb = ((size_t)((kc * 16 + nt) * 64 + lane)) * 8;
            s8v bh = *(const s8v*)&B2[0][bb];
            s8v bl = *(const s8v*)&B2[1][bb];
#pragma unroll
            for (int s = 0; s < 2; ++s) {
                acc[s][nt] = __builtin_amdgcn_mfma_f32_16x16x32_bf16(Ah[s], bh, acc[s][nt], 0, 0, 0);
                acc[s][nt] = __builtin_amdgcn_mfma_f32_16x16x32_bf16(Al[s], bh, acc[s][nt], 0, 0, 0);
                acc[s][nt] = __builtin_amdgcn_mfma_f32_16x16x32_bf16(Ah[s], bl, acc[s][nt], 0, 0, 0);
            }
        }
    }

    // ---- epilogue: store PH/PT + fused qh/qt = P . Wa2 ----
    // Wa2 has 128 elements; tile nt (0..15) maps to Wa2 column (nt&7)*16+l15.
    float wa2v[8];
#pragma unroll
    for (int c8 = 0; c8 < 8; ++c8) wa2v[c8] = Wa2[c8 * 16 + l15];

#pragma unroll
    for (int s = 0; s < 2; ++s) {
        int rowb = m0 + s * 16 + lg * 4;
        float qhp[4] = {0.f, 0.f, 0.f, 0.f};
        float qtp[4] = {0.f, 0.f, 0.f, 0.f};
#pragma unroll
        for (int nt = 0; nt < 16; ++nt) {
#pragma unroll
            for (int g = 0; g < 4; ++g) {
                float v = acc[s][nt][g];
                if (nt < 8) qhp[g] += v * wa2v[nt];
                else        qtp[g] += v * wa2v[nt & 7];
                int row = rowb + g;
                if (row < N_ENT) {
                    if (nt < 8) PH[(size_t)row * DIM + nt * 16 + l15] = v;
                    else        PT[(size_t)row * DIM + (nt - 8) * 16 + l15] = v;
                }
            }
        }
#pragma unroll
        for (int g = 0; g < 4; ++g) {
            float a = qhp[g], b = qtp[g];
#pragma unroll
            for (int m = 1; m <= 8; m <<= 1) {
                a += __shfl_xor(a, m);
                b += __shfl_xor(b, m);
            }
            int row = rowb + g;
            if (l15 == 0 && row < N_ENT) { qh[row] = a; qt[row] = b; }
        }
    }
}

// ---------------------------------------------------------------------------
// K3: deg[h]++ per edge
__global__ __launch_bounds__(256) void k_count(const int* __restrict__ trip,
                                               int* __restrict__ deg) {
    int e = blockIdx.x * 256 + threadIdx.x;
    if (e < N_EDGES) atomicAdd(&deg[trip[e * 3]], 1);
}

// ---------------------------------------------------------------------------
// scan: block partial sums
__global__ __launch_bounds__(SC_T) void k_scan1(const int* __restrict__ deg,
                                                int* __restrict__ partial) {
    int b = blockIdx.x, t = threadIdx.x;
    int i0 = b * SC_CHUNK + t * SC_C;
    int s = deg[i0] + deg[i0 + 1];
#pragma unroll
    for (int m = 1; m <= 32; m <<= 1) s += __shfl_xor(s, m);
    __shared__ int ws_[SC_T / 64];
    int lane = t & 63, wid = t >> 6;
    if (lane == 0) ws_[wid] = s;
    __syncthreads();
    if (t == 0) {
        int tot = 0;
        for (int w = 0; w < SC_T / 64; ++w) tot += ws_[w];
        partial[b] = tot;
    }
}

// scan of block partials (1 block)
__global__ __launch_bounds__(SC_T) void k_scan2(const int* __restrict__ partial,
                                                int* __restrict__ base,
                                                int* __restrict__ off) {
    __shared__ int s[SC_T];
    int t = threadIdx.x;
    int v = (t < SC_B) ? partial[t] : 0;
    s[t] = v;
    __syncthreads();
    for (int d = 1; d < SC_T; d <<= 1) {
        int u = (t >= d) ? s[t - d] : 0;
        __syncthreads();
        s[t] += u;
        __syncthreads();
    }
    if (t < SC_B) base[t] = s[t] - v;
    if (t == SC_T - 1) off[N_ENT] = s[t];
}

// per-block rescan -> off, cur
__global__ __launch_bounds__(SC_T) void k_scan3(const int* __restrict__ deg,
                                                const int* __restrict__ base,
                                                int* __restrict__ off,
                                                int* __restrict__ cur) {
    __shared__ int s[SC_T];
    int b = blockIdx.x, t = threadIdx.x;
    int i0 = b * SC_CHUNK + t * SC_C;
    int d0 = deg[i0], d1 = deg[i0 + 1];
    int tsum = d0 + d1;
    s[t] = tsum;
    __syncthreads();
    for (int d = 1; d < SC_T; d <<= 1) {
        int u = (t >= d) ? s[t - d] : 0;
        __syncthreads();
        s[t] += u;
        __syncthreads();
    }
    int excl = s[t] - tsum + base[b];
    if (i0 < N_ENT)     { off[i0] = excl;          cur[i0] = excl; }
    if (i0 + 1 < N_ENT) { off[i0 + 1] = excl + d0; cur[i0 + 1] = excl + d0; }
}

// ---------------------------------------------------------------------------
// K6: per edge: w = exp(leaky(qh+qr+qt+ba2)); CSR-scatter packed (r,t) + w as float2
__global__ __launch_bounds__(256) void k_scatter(const int* __restrict__ trip,
                                                 const float* __restrict__ qh,
                                                 const float* __restrict__ qt,
                                                 const float* __restrict__ qr,
                                                 const float* __restrict__ ba2,
                                                 int* __restrict__ cur,
                                                 float2* __restrict__ pkw) {
    int e = blockIdx.x * 256 + threadIdx.x;
    if (e >= N_EDGES) return;
    int h  = trip[e * 3 + 0];
    int tl = trip[e * 3 + 1];
    int r  = trip[e * 3 + 2];
    float b = qh[h] + qt[tl] + qr[r] + ba2[0];
    float lr = b > 0.f ? b : 0.01f * b;
    float w = expf(lr);
    int pos = atomicAdd(&cur[h], 1);
    float2 v;
    v.x = __uint_as_float(((unsigned)r << 17) | (unsigned)tl);
    v.y = w;
    pkw[pos] = v;
}

// ---------------------------------------------------------------------------
// K7: per head (32 lanes): acc = sum w*(PR[r]+PT[t]); out = elu((acc+sw*PH[h])/sw')
__global__ __launch_bounds__(256) void k_gather(const int* __restrict__ off,
                                                const float2* __restrict__ pkw,
                                                const float* __restrict__ PH,
                                                const float* __restrict__ PR,
                                                const float* __restrict__ PT,
                                                float* __restrict__ out) {
    int idx = blockIdx.x * 256 + threadIdx.x;
    int i = idx >> 5, lane = idx & 31;
    if (i >= N_ENT) return;
    int lane4 = lane * 4;
    int e0 = off[i], e1 = off[i + 1];
    float4 acc = make_float4(0.f, 0.f, 0.f, 0.f);
    float sw = 0.f;
    for (int e = e0; e < e1; ++e) {
        float2 pw = pkw[e];
        unsigned p = __float_as_uint(pw.x);
        float w = pw.y;
        int tt = (int)(p & 0x1FFFFu);
        int rr = (int)(p >> 17);
        float4 pr = *(const float4*)&PR[(size_t)rr * DIM + lane4];
        float4 pt = *(const float4*)&PT[(size_t)tt * DIM + lane4];
        acc.x += w * (pr.x + pt.x);
        acc.y += w * (pr.y + pt.y);
        acc.z += w * (pr.z + pt.z);
        acc.w += w * (pr.w + pt.w);
        sw += w;
    }
    float4 ph = *(const float4*)&PH[(size_t)i * DIM + lane4];
    acc.x += sw * ph.x; acc.y += sw * ph.y;
    acc.z += sw * ph.z; acc.w += sw * ph.w;
    float den = (sw == 0.f) ? 1e-12f : sw;
    float inv = 1.f / den;
    float vx = acc.x * inv, vy = acc.y * inv, vz = acc.z * inv, vw = acc.w * inv;
    vx = vx > 0.f ? vx : expm1f(vx);
    vy = vy > 0.f ? vy : expm1f(vy);
    vz = vz > 0.f ? vz : expm1f(vz);
    vw = vw > 0.f ? vw : expm1f(vw);
    *(float4*)&out[(size_t)i * DIM + lane4] = make_float4(vx, vy, vz, vw);
}

// ---------------------------------------------------------------------------
extern "C" void kernel_launch(void* const* d_in, const int* in_sizes, int n_in,
                              void* d_out, int out_size, void* d_ws, size_t ws_size,
                              hipStream_t stream) {
    const int*   trip = (const int*)d_in[0];
    const float* ent  = (const float*)d_in[1];
    const float* rel  = (const float*)d_in[2];
    const float* Wa   = (const float*)d_in[3];
    const float* ba   = (const float*)d_in[4];
    const float* Wa2  = (const float*)d_in[5];
    const float* ba2  = (const float*)d_in[6];
    float* out = (float*)d_out;

    float* ws = (float*)d_ws;
    size_t o = 0;
    float* PH = ws + o;        o += (size_t)N_ENT * DIM;
    float* PT = ws + o;        o += (size_t)N_ENT * DIM;
    float* PR = ws + o;        o += (size_t)N_REL * DIM;
    float* qh = ws + o;        o += N_ENT;
    float* qt = ws + o;        o += N_ENT;
    float* qr = ws + o;        o += N_REL + 3;          // keep alignment even
    int*   deg = (int*)(ws + o);      o += DEG_PAD;
    int*   off = (int*)(ws + o);      o += N_ENT + 1;
    int*   cur = (int*)(ws + o);      o += N_ENT + 1;
    int*   partial = (int*)(ws + o);  o += SC_T;
    int*   base = (int*)(ws + o);     o += SC_T;
    float2* pkw = (float2*)(ws + o);  o += (size_t)N_EDGES * 2;

    hipMemsetAsync(deg, 0, (size_t)DEG_PAD * sizeof(int), stream);

    k_rel<<<N_REL, 128, 0, stream>>>(rel, Wa, ba, Wa2, PR, qr);
    k_ent_mfma<<<(N_ENT + MT - 1) / MT, 512, 0, stream>>>(ent, Wa, Wa2, PH, PT, qh, qt);
    k_count<<<(N_EDGES + 255) / 256, 256, 0, stream>>>(trip, deg);
    k_scan1<<<SC_B, SC_T, 0, stream>>>(deg, partial);
    k_scan2<<<1, SC_T, 0, stream>>>(partial, base, off);
    k_scan3<<<SC_B, SC_T, 0, stream>>>(deg, base, off, cur);
    k_scatter<<<(N_EDGES + 255) / 256, 256, 0, stream>>>(trip, qh, qt, qr, ba2, cur, pkw);
    k_gather<<<(N_ENT * 32) / 256, 256, 0, stream>>>(off, pkw, PH, PR, PT, out);
}

// Round 9
// 197.112 us; speedup vs baseline: 9.0056x; 1.1342x over previous
//
#include <hip/hip_runtime.h>

#define N_ENT   100000
#define N_REL   500
#define N_EDGES 800000
#define DIM     128
#define WA_LD   384

// scan config
#define SC_T 256
#define SC_C 2
#define SC_CHUNK (SC_T * SC_C)                      // 512
#define SC_B ((N_ENT + SC_CHUNK - 1) / SC_CHUNK)    // 196
#define DEG_PAD (SC_B * SC_CHUNK)                   // 100352

typedef __attribute__((ext_vector_type(8))) short  s8v;   // 8 bf16 (4 VGPR)
typedef __attribute__((ext_vector_type(4))) float  f4v;   // MFMA acc

__device__ __forceinline__ unsigned short f2bf(float x) {
    unsigned u = __float_as_uint(x);
    return (unsigned short)((u + 0x7FFFu + ((u >> 16) & 1u)) >> 16);
}
__device__ __forceinline__ float bf2f(unsigned short h) {
    return __uint_as_float(((unsigned)h) << 16);
}

// ---------------------------------------------------------------------------
// K1: PR[r][j] = ba[j] + sum_k rel[r][k] * Wa[j][128+k]; qr[r] = dot(PR[r], Wa2)
__global__ __launch_bounds__(128) void k_rel(const float* __restrict__ rel,
                                             const float* __restrict__ Wa,
                                             const float* __restrict__ ba,
                                             const float* __restrict__ Wa2,
                                             float* __restrict__ PR,
                                             float* __restrict__ qr) {
    int r = blockIdx.x;
    int j = threadIdx.x;
    __shared__ float relrow[DIM];
    __shared__ float red[DIM];
    relrow[j] = rel[r * DIM + j];
    __syncthreads();
    const float* wrow = Wa + (size_t)j * WA_LD + 128;
    float acc = ba[j];
#pragma unroll 8
    for (int k = 0; k < DIM; ++k) acc += relrow[k] * wrow[k];
    PR[r * DIM + j] = acc;
    red[j] = acc * Wa2[j];
    __syncthreads();
    for (int s = 64; s > 0; s >>= 1) {
        if (j < s) red[j] += red[j + s];
        __syncthreads();
    }
    if (j == 0) qr[r] = red[0];
}

// ---------------------------------------------------------------------------
// K2 (MFMA): C[100000x256] = ent[100000x128] @ [Wh | Wt]  (fp32 via bf16 split:
// AhBh + AhBl + AlBh). Weights staged once/block in LDS in exact B-fragment
// order. 512 threads / 8 waves x 32 rows = 256 rows/block.
// Round 7 change: PT is stored as bf16 (PTb) -- its only consumer is the
// gather's convex combination, where bf16 adds ~0.01 absmax. Halves both the
// PT write traffic here and the random-gather traffic in k_gather.
#define MT 256
__global__ __launch_bounds__(512, 1) void k_ent_mfma(const float* __restrict__ ent,
                                                     const float* __restrict__ Wa,
                                                     const float* __restrict__ Wa2,
                                                     float* __restrict__ PH,
                                                     unsigned short* __restrict__ PTb,
                                                     float* __restrict__ qh,
                                                     float* __restrict__ qt) {
    __shared__ short B2[2][32768];   // [hi/lo][ ((kc*16+nt)*64 + lane)*8 + e ] : 128 KB
    int t = threadIdx.x;

    // ---- stage weights once per block ----
#pragma unroll
    for (int tt = 0; tt < 2; ++tt) {
#pragma unroll
        for (int it = 0; it < 4; ++it) {
            int g = t + 512 * it;        // granule 0..2047: 8 consecutive k of col j
            int j = g >> 4;              // 0..127 (output col within table)
            int k8 = g & 15;             // which 8-float k-granule
            const float* src = Wa + (size_t)j * WA_LD + tt * 256 + k8 * 8;
            float4 v0 = *(const float4*)src;
            float4 v1 = *(const float4*)(src + 4);
            float x[8] = {v0.x, v0.y, v0.z, v0.w, v1.x, v1.y, v1.z, v1.w};
            s8v hv, lv;
#pragma unroll
            for (int e = 0; e < 8; ++e) {
                unsigned short hb = f2bf(x[e]);
                hv[e] = (short)hb;
                lv[e] = (short)f2bf(x[e] - bf2f(hb));
            }
            int col = tt * 128 + j;
            int kc = k8 >> 2;
            int lanep = (k8 & 3) * 16 + (col & 15);
            int nt = col >> 4;
            size_t base = ((size_t)((kc * 16 + nt) * 64 + lanep)) * 8;
            *(s8v*)&B2[0][base] = hv;
            *(s8v*)&B2[1][base] = lv;
        }
    }

    int wv = t >> 6;                 // wave 0..7
    int lane = t & 63;
    int l15 = lane & 15, lg = lane >> 4;
    int m0 = blockIdx.x * MT + wv * 32;

    f4v acc[2][16];
#pragma unroll
    for (int s = 0; s < 2; ++s)
#pragma unroll
        for (int nt = 0; nt < 16; ++nt)
            acc[s][nt] = (f4v){0.f, 0.f, 0.f, 0.f};

    __syncthreads();

#pragma unroll
    for (int kc = 0; kc < 4; ++kc) {
        s8v Ah[2], Al[2];
#pragma unroll
        for (int s = 0; s < 2; ++s) {
            int row = m0 + s * 16 + l15;
            if (row < N_ENT) {
                const float* ap = ent + (size_t)row * DIM + kc * 32 + lg * 8;
                float4 v0 = *(const float4*)ap;
                float4 v1 = *(const float4*)(ap + 4);
                float x[8] = {v0.x, v0.y, v0.z, v0.w, v1.x, v1.y, v1.z, v1.w};
#pragma unroll
                for (int e = 0; e < 8; ++e) {
                    unsigned short hb = f2bf(x[e]);
                    Ah[s][e] = (short)hb;
                    Al[s][e] = (short)f2bf(x[e] - bf2f(hb));
                }
            } else {
                Ah[s] = (s8v){0, 0, 0, 0, 0, 0, 0, 0};
                Al[s] = (s8v){0, 0, 0, 0, 0, 0, 0, 0};
            }
        }
#pragma unroll
        for (int nt = 0; nt < 16; ++nt) {
            size_t bb = ((size_t)((kc * 16 + nt) * 64 + lane)) * 8;
            s8v bh = *(const s8v*)&B2[0][bb];
            s8v bl = *(const s8v*)&B2[1][bb];
#pragma unroll
            for (int s = 0; s < 2; ++s) {
                acc[s][nt] = __builtin_amdgcn_mfma_f32_16x16x32_bf16(Ah[s], bh, acc[s][nt], 0, 0, 0);
                acc[s][nt] = __builtin_amdgcn_mfma_f32_16x16x32_bf16(Al[s], bh, acc[s][nt], 0, 0, 0);
                acc[s][nt] = __builtin_amdgcn_mfma_f32_16x16x32_bf16(Ah[s], bl, acc[s][nt], 0, 0, 0);
            }
        }
    }

    // ---- epilogue: store PH (f32) / PTb (bf16) + fused qh/qt = P . Wa2 ----
    float wa2v[8];
#pragma unroll
    for (int c8 = 0; c8 < 8; ++c8) wa2v[c8] = Wa2[c8 * 16 + l15];

#pragma unroll
    for (int s = 0; s < 2; ++s) {
        int rowb = m0 + s * 16 + lg * 4;
        float qhp[4] = {0.f, 0.f, 0.f, 0.f};
        float qtp[4] = {0.f, 0.f, 0.f, 0.f};
#pragma unroll
        for (int nt = 0; nt < 16; ++nt) {
#pragma unroll
            for (int g = 0; g < 4; ++g) {
                float v = acc[s][nt][g];
                if (nt < 8) qhp[g] += v * wa2v[nt];
                else        qtp[g] += v * wa2v[nt & 7];
                int row = rowb + g;
                if (row < N_ENT) {
                    if (nt < 8) PH[(size_t)row * DIM + nt * 16 + l15] = v;
                    else        PTb[(size_t)row * DIM + (nt - 8) * 16 + l15] = f2bf(v);
                }
            }
        }
#pragma unroll
        for (int g = 0; g < 4; ++g) {
            float a = qhp[g], b = qtp[g];
#pragma unroll
            for (int m = 1; m <= 8; m <<= 1) {
                a += __shfl_xor(a, m);
                b += __shfl_xor(b, m);
            }
            int row = rowb + g;
            if (l15 == 0 && row < N_ENT) { qh[row] = a; qt[row] = b; }
        }
    }
}

// ---------------------------------------------------------------------------
// K3: deg[h]++ per edge
__global__ __launch_bounds__(256) void k_count(const int* __restrict__ trip,
                                               int* __restrict__ deg) {
    int e = blockIdx.x * 256 + threadIdx.x;
    if (e < N_EDGES) atomicAdd(&deg[trip[e * 3]], 1);
}

// ---------------------------------------------------------------------------
// scan: block partial sums
__global__ __launch_bounds__(SC_T) void k_scan1(const int* __restrict__ deg,
                                                int* __restrict__ partial) {
    int b = blockIdx.x, t = threadIdx.x;
    int i0 = b * SC_CHUNK + t * SC_C;
    int s = deg[i0] + deg[i0 + 1];
#pragma unroll
    for (int m = 1; m <= 32; m <<= 1) s += __shfl_xor(s, m);
    __shared__ int ws_[SC_T / 64];
    int lane = t & 63, wid = t >> 6;
    if (lane == 0) ws_[wid] = s;
    __syncthreads();
    if (t == 0) {
        int tot = 0;
        for (int w = 0; w < SC_T / 64; ++w) tot += ws_[w];
        partial[b] = tot;
    }
}

// scan of block partials (1 block)
__global__ __launch_bounds__(SC_T) void k_scan2(const int* __restrict__ partial,
                                                int* __restrict__ base,
                                                int* __restrict__ off) {
    __shared__ int s[SC_T];
    int t = threadIdx.x;
    int v = (t < SC_B) ? partial[t] : 0;
    s[t] = v;
    __syncthreads();
    for (int d = 1; d < SC_T; d <<= 1) {
        int u = (t >= d) ? s[t - d] : 0;
        __syncthreads();
        s[t] += u;
        __syncthreads();
    }
    if (t < SC_B) base[t] = s[t] - v;
    if (t == SC_T - 1) off[N_ENT] = s[t];
}

// per-block rescan -> off, cur
__global__ __launch_bounds__(SC_T) void k_scan3(const int* __restrict__ deg,
                                                const int* __restrict__ base,
                                                int* __restrict__ off,
                                                int* __restrict__ cur) {
    __shared__ int s[SC_T];
    int b = blockIdx.x, t = threadIdx.x;
    int i0 = b * SC_CHUNK + t * SC_C;
    int d0 = deg[i0], d1 = deg[i0 + 1];
    int tsum = d0 + d1;
    s[t] = tsum;
    __syncthreads();
    for (int d = 1; d < SC_T; d <<= 1) {
        int u = (t >= d) ? s[t - d] : 0;
        __syncthreads();
        s[t] += u;
        __syncthreads();
    }
    int excl = s[t] - tsum + base[b];
    if (i0 < N_ENT)     { off[i0] = excl;          cur[i0] = excl; }
    if (i0 + 1 < N_ENT) { off[i0 + 1] = excl + d0; cur[i0 + 1] = excl + d0; }
}

// ---------------------------------------------------------------------------
// K6: per edge: w = exp(leaky(qh+qr+qt+ba2)); CSR-scatter packed (r,t) + w as float2
__global__ __launch_bounds__(256) void k_scatter(const int* __restrict__ trip,
                                                 const float* __restrict__ qh,
                                                 const float* __restrict__ qt,
                                                 const float* __restrict__ qr,
                                                 const float* __restrict__ ba2,
                                                 int* __restrict__ cur,
                                                 float2* __restrict__ pkw) {
    int e = blockIdx.x * 256 + threadIdx.x;
    if (e >= N_EDGES) return;
    int h  = trip[e * 3 + 0];
    int tl = trip[e * 3 + 1];
    int r  = trip[e * 3 + 2];
    float b = qh[h] + qt[tl] + qr[r] + ba2[0];
    float lr = b > 0.f ? b : 0.01f * b;
    float w = expf(lr);
    int pos = atomicAdd(&cur[h], 1);
    float2 v;
    v.x = __uint_as_float(((unsigned)r << 17) | (unsigned)tl);
    v.y = w;
    pkw[pos] = v;
}

// ---------------------------------------------------------------------------
// K7: per head (32 lanes): acc = sum w*(PR[r]+PTb[t]); out = elu((acc+sw*PH[h])/sw')
// PTb is bf16 (8B/lane gather, 256B/row); 2-way unrolled for MLP.
__global__ __launch_bounds__(256) void k_gather(const int* __restrict__ off,
                                                const float2* __restrict__ pkw,
                                                const float* __restrict__ PH,
                                                const float* __restrict__ PR,
                                                const unsigned short* __restrict__ PTb,
                                                float* __restrict__ out) {
    int idx = blockIdx.x * 256 + threadIdx.x;
    int i = idx >> 5, lane = idx & 31;
    if (i >= N_ENT) return;
    int lane4 = lane * 4;
    int e0 = off[i], e1 = off[i + 1];
    float4 acc = make_float4(0.f, 0.f, 0.f, 0.f);
    float sw = 0.f;
    int e = e0;
    for (; e + 1 < e1; e += 2) {
        float2 pw0 = pkw[e];
        float2 pw1 = pkw[e + 1];
        unsigned p0 = __float_as_uint(pw0.x);
        unsigned p1 = __float_as_uint(pw1.x);
        float w0 = pw0.y, w1 = pw1.y;
        int t0 = (int)(p0 & 0x1FFFFu), r0 = (int)(p0 >> 17);
        int t1 = (int)(p1 & 0x1FFFFu), r1 = (int)(p1 >> 17);
        ushort4 b0 = *(const ushort4*)&PTb[(size_t)t0 * DIM + lane4];
        ushort4 b1 = *(const ushort4*)&PTb[(size_t)t1 * DIM + lane4];
        float4 pr0 = *(const float4*)&PR[(size_t)r0 * DIM + lane4];
        float4 pr1 = *(const float4*)&PR[(size_t)r1 * DIM + lane4];
        acc.x += w0 * (pr0.x + bf2f(b0.x)) + w1 * (pr1.x + bf2f(b1.x));
        acc.y += w0 * (pr0.y + bf2f(b0.y)) + w1 * (pr1.y + bf2f(b1.y));
        acc.z += w0 * (pr0.z + bf2f(b0.z)) + w1 * (pr1.z + bf2f(b1.z));
        acc.w += w0 * (pr0.w + bf2f(b0.w)) + w1 * (pr1.w + bf2f(b1.w));
        sw += w0 + w1;
    }
    if (e < e1) {
        float2 pw = pkw[e];
        unsigned p = __float_as_uint(pw.x);
        float w = pw.y;
        int tt = (int)(p & 0x1FFFFu), rr = (int)(p >> 17);
        ushort4 b = *(const ushort4*)&PTb[(size_t)tt * DIM + lane4];
        float4 pr = *(const float4*)&PR[(size_t)rr * DIM + lane4];
        acc.x += w * (pr.x + bf2f(b.x));
        acc.y += w * (pr.y + bf2f(b.y));
        acc.z += w * (pr.z + bf2f(b.z));
        acc.w += w * (pr.w + bf2f(b.w));
        sw += w;
    }
    float4 ph = *(const float4*)&PH[(size_t)i * DIM + lane4];
    acc.x += sw * ph.x; acc.y += sw * ph.y;
    acc.z += sw * ph.z; acc.w += sw * ph.w;
    float den = (sw == 0.f) ? 1e-12f : sw;
    float inv = 1.f / den;
    float vx = acc.x * inv, vy = acc.y * inv, vz = acc.z * inv, vw = acc.w * inv;
    vx = vx > 0.f ? vx : expm1f(vx);
    vy = vy > 0.f ? vy : expm1f(vy);
    vz = vz > 0.f ? vz : expm1f(vz);
    vw = vw > 0.f ? vw : expm1f(vw);
    *(float4*)&out[(size_t)i * DIM + lane4] = make_float4(vx, vy, vz, vw);
}

// ---------------------------------------------------------------------------
extern "C" void kernel_launch(void* const* d_in, const int* in_sizes, int n_in,
                              void* d_out, int out_size, void* d_ws, size_t ws_size,
                              hipStream_t stream) {
    const int*   trip = (const int*)d_in[0];
    const float* ent  = (const float*)d_in[1];
    const float* rel  = (const float*)d_in[2];
    const float* Wa   = (const float*)d_in[3];
    const float* ba   = (const float*)d_in[4];
    const float* Wa2  = (const float*)d_in[5];
    const float* ba2  = (const float*)d_in[6];
    float* out = (float*)d_out;

    float* ws = (float*)d_ws;
    size_t o = 0;
    float* PH = ws + o;        o += (size_t)N_ENT * DIM;
    unsigned short* PTb = (unsigned short*)(ws + o); o += (size_t)N_ENT * DIM / 2;
    float* PR = ws + o;        o += (size_t)N_REL * DIM;
    float* qh = ws + o;        o += N_ENT;
    float* qt = ws + o;        o += N_ENT;
    float* qr = ws + o;        o += N_REL + 3;          // keep alignment even
    int*   deg = (int*)(ws + o);      o += DEG_PAD;
    int*   off = (int*)(ws + o);      o += N_ENT + 1;
    int*   cur = (int*)(ws + o);      o += N_ENT + 1;
    int*   partial = (int*)(ws + o);  o += SC_T;
    int*   base = (int*)(ws + o);     o += SC_T;
    float2* pkw = (float2*)(ws + o);  o += (size_t)N_EDGES * 2;

    hipMemsetAsync(deg, 0, (size_t)DEG_PAD * sizeof(int), stream);

    k_rel<<<N_REL, 128, 0, stream>>>(rel, Wa, ba, Wa2, PR, qr);
    k_ent_mfma<<<(N_ENT + MT - 1) / MT, 512, 0, stream>>>(ent, Wa, Wa2, PH, PTb, qh, qt);
    k_count<<<(N_EDGES + 255) / 256, 256, 0, stream>>>(trip, deg);
    k_scan1<<<SC_B, SC_T, 0, stream>>>(deg, partial);
    k_scan2<<<1, SC_T, 0, stream>>>(partial, base, off);
    k_scan3<<<SC_B, SC_T, 0, stream>>>(deg, base, off, cur);
    k_scatter<<<(N_EDGES + 255) / 256, 256, 0, stream>>>(trip, qh, qt, qr, ba2, cur, pkw);
    k_gather<<<(N_ENT * 32) / 256, 256, 0, stream>>>(off, pkw, PH, PR, PTb, out);
}

// Round 11
// 183.607 us; speedup vs baseline: 9.6679x; 1.0736x over previous
//
#include <hip/hip_runtime.h>

#define N_ENT   100000
#define N_REL   500
#define N_EDGES 800000
#define DIM     128
#define WA_LD   384

#define MT       256
#define ENT_BLKS 391   // ceil(N_ENT/MT)
#define REL_BLKS 63    // 8 relations per block (8 waves), ceil(500/8)

// scan config
#define SC_T 256
#define SC_C 2
#define SC_CHUNK (SC_T * SC_C)                      // 512
#define SC_B ((N_ENT + SC_CHUNK - 1) / SC_CHUNK)    // 196
#define DEG_PAD (SC_B * SC_CHUNK)                   // 100352

typedef __attribute__((ext_vector_type(8))) short  s8v;   // 8 bf16 (4 VGPR)
typedef __attribute__((ext_vector_type(4))) float  f4v;   // MFMA acc

__device__ __forceinline__ unsigned short f2bf(float x) {
    unsigned u = __float_as_uint(x);
    return (unsigned short)((u + 0x7FFFu + ((u >> 16) & 1u)) >> 16);
}
__device__ __forceinline__ float bf2f(unsigned short h) {
    return __uint_as_float(((unsigned)h) << 16);
}

// ---------------------------------------------------------------------------
// K0: pre-convert [Wh | Wt] to bf16 in exact B-fragment order (one tiny block).
// B frag at lane l, elem e is B[kc*32 + (l>>4)*8 + e][nt*16 + (l&15)];
// stored at ((kc*16+nt)*64 + l)*8 + e.
__global__ __launch_bounds__(512) void k_prep(const float* __restrict__ Wa,
                                              short* __restrict__ Bg) {
    int t = threadIdx.x;
#pragma unroll
    for (int tt = 0; tt < 2; ++tt) {
#pragma unroll
        for (int it = 0; it < 4; ++it) {
            int g = t + 512 * it;        // 0..2047
            int j = g >> 4;              // col within table
            int k8 = g & 15;             // 8-float k-granule
            const float* src = Wa + (size_t)j * WA_LD + tt * 256 + k8 * 8;
            float4 v0 = *(const float4*)src;
            float4 v1 = *(const float4*)(src + 4);
            float x[8] = {v0.x, v0.y, v0.z, v0.w, v1.x, v1.y, v1.z, v1.w};
            s8v hv;
#pragma unroll
            for (int e = 0; e < 8; ++e) hv[e] = (short)f2bf(x[e]);
            int col = tt * 128 + j;
            int kc = k8 >> 2;
            int lanep = (k8 & 3) * 16 + (col & 15);
            int nt = col >> 4;
            *(s8v*)&Bg[((size_t)((kc * 16 + nt) * 64 + lanep)) * 8] = hv;
        }
    }
}

// ---------------------------------------------------------------------------
// K1 (fused): blocks [0,391): MFMA projection PHb/PTb (bf16) + fused qh/qt
//             + 4 edge-count atomics per thread (issued after compute).
//             blocks [391,454): rel projection PR (f32) + qr, 1 wave/relation
//             (8 waves/block, r = rb*8+wv, guarded r < N_REL).
// Ent path: no LDS, no barriers; B fragments read from L2-resident Bg.
__global__ __launch_bounds__(512) void k_fused(const float* __restrict__ ent,
                                               const short* __restrict__ Bg,
                                               const float* __restrict__ Wa2,
                                               unsigned short* __restrict__ PHb,
                                               unsigned short* __restrict__ PTb,
                                               float* __restrict__ qh,
                                               float* __restrict__ qt,
                                               const int* __restrict__ trip,
                                               int* __restrict__ deg,
                                               const float* __restrict__ rel,
                                               const float* __restrict__ Wa,
                                               const float* __restrict__ ba,
                                               float* __restrict__ PR,
                                               float* __restrict__ qr) {
    __shared__ float relLds[8][128];
    int t = threadIdx.x;
    int wv = t >> 6;                 // wave 0..7
    int lane = t & 63;

    if (blockIdx.x >= ENT_BLKS) {
        // ---------------- rel path: relation r = rb*8 + wv ----------------
        int rb = blockIdx.x - ENT_BLKS;
        int r = rb * 8 + wv;
        if (r < N_REL) {
            // wave-private LDS row; write->read within the same wave, no barrier
            relLds[wv][lane]      = rel[r * DIM + lane];
            relLds[wv][64 + lane] = rel[r * DIM + 64 + lane];
            int j0 = 2 * lane, j1 = j0 + 1;
            const float* w0 = Wa + (size_t)j0 * WA_LD + 128;
            const float* w1 = Wa + (size_t)j1 * WA_LD + 128;
            float a0 = ba[j0], a1 = ba[j1];
#pragma unroll 8
            for (int k4 = 0; k4 < 32; ++k4) {
                float4 rv = *(const float4*)&relLds[wv][4 * k4];
                float4 x0 = *(const float4*)&w0[4 * k4];
                float4 x1 = *(const float4*)&w1[4 * k4];
                a0 += rv.x * x0.x + rv.y * x0.y + rv.z * x0.z + rv.w * x0.w;
                a1 += rv.x * x1.x + rv.y * x1.y + rv.z * x1.z + rv.w * x1.w;
            }
            *(float2*)&PR[(size_t)r * DIM + j0] = make_float2(a0, a1);
            float p = a0 * Wa2[j0] + a1 * Wa2[j1];
#pragma unroll
            for (int m = 1; m <= 32; m <<= 1) p += __shfl_xor(p, m);
            if (lane == 0) qr[r] = p;
        }
        return;
    }

    // ---------------- ent path ----------------
    int l15 = lane & 15, lg = lane >> 4;
    int m0 = blockIdx.x * MT + wv * 32;

    f4v acc[2][16];
#pragma unroll
    for (int s = 0; s < 2; ++s)
#pragma unroll
        for (int nt = 0; nt < 16; ++nt)
            acc[s][nt] = (f4v){0.f, 0.f, 0.f, 0.f};

#pragma unroll
    for (int kc = 0; kc < 4; ++kc) {
        s8v Ah[2];
#pragma unroll
        for (int s = 0; s < 2; ++s) {
            int row = m0 + s * 16 + l15;
            if (row < N_ENT) {
                const float* ap = ent + (size_t)row * DIM + kc * 32 + lg * 8;
                float4 v0 = *(const float4*)ap;
                float4 v1 = *(const float4*)(ap + 4);
                float x[8] = {v0.x, v0.y, v0.z, v0.w, v1.x, v1.y, v1.z, v1.w};
#pragma unroll
                for (int e = 0; e < 8; ++e) Ah[s][e] = (short)f2bf(x[e]);
            } else {
                Ah[s] = (s8v){0, 0, 0, 0, 0, 0, 0, 0};
            }
        }
#pragma unroll
        for (int nt = 0; nt < 16; ++nt) {
            s8v bg = *(const s8v*)&Bg[((size_t)((kc * 16 + nt) * 64 + lane)) * 8];
            acc[0][nt] = __builtin_amdgcn_mfma_f32_16x16x32_bf16(Ah[0], bg, acc[0][nt], 0, 0, 0);
            acc[1][nt] = __builtin_amdgcn_mfma_f32_16x16x32_bf16(Ah[1], bg, acc[1][nt], 0, 0, 0);
        }
    }

    // epilogue: bf16 stores + fused qh/qt = P . Wa2 (tile nt -> Wa2 col (nt&7)*16+l15)
    float wa2v[8];
#pragma unroll
    for (int c8 = 0; c8 < 8; ++c8) wa2v[c8] = Wa2[c8 * 16 + l15];

#pragma unroll
    for (int s = 0; s < 2; ++s) {
        int rowb = m0 + s * 16 + lg * 4;
        float qhp[4] = {0.f, 0.f, 0.f, 0.f};
        float qtp[4] = {0.f, 0.f, 0.f, 0.f};
#pragma unroll
        for (int nt = 0; nt < 16; ++nt) {
#pragma unroll
            for (int g = 0; g < 4; ++g) {
                float v = acc[s][nt][g];
                if (nt < 8) qhp[g] += v * wa2v[nt];
                else        qtp[g] += v * wa2v[nt & 7];
                int row = rowb + g;
                if (row < N_ENT) {
                    if (nt < 8) PHb[(size_t)row * DIM + nt * 16 + l15] = f2bf(v);
                    else        PTb[(size_t)row * DIM + (nt - 8) * 16 + l15] = f2bf(v);
                }
            }
        }
#pragma unroll
        for (int g = 0; g < 4; ++g) {
            float a = qhp[g], b = qtp[g];
#pragma unroll
            for (int m = 1; m <= 8; m <<= 1) {
                a += __shfl_xor(a, m);
                b += __shfl_xor(b, m);
            }
            int row = rowb + g;
            if (l15 == 0 && row < N_ENT) { qh[row] = a; qt[row] = b; }
        }
    }

    // fused edge-count (after compute so vmcnt waits don't stall MFMA)
    int tid = blockIdx.x * 512 + t;
    int eb = tid * 4;
#pragma unroll
    for (int je = 0; je < 4; ++je) {
        int e = eb + je;
        if (e < N_EDGES) atomicAdd(&deg[trip[e * 3]], 1);
    }
}

// ---------------------------------------------------------------------------
// scan: block partial sums
__global__ __launch_bounds__(SC_T) void k_scan1(const int* __restrict__ deg,
                                                int* __restrict__ partial) {
    int b = blockIdx.x, t = threadIdx.x;
    int i0 = b * SC_CHUNK + t * SC_C;
    int s = deg[i0] + deg[i0 + 1];
#pragma unroll
    for (int m = 1; m <= 32; m <<= 1) s += __shfl_xor(s, m);
    __shared__ int ws_[SC_T / 64];
    int lane = t & 63, wid = t >> 6;
    if (lane == 0) ws_[wid] = s;
    __syncthreads();
    if (t == 0) {
        int tot = 0;
        for (int w = 0; w < SC_T / 64; ++w) tot += ws_[w];
        partial[b] = tot;
    }
}

// scan of block partials (1 block)
__global__ __launch_bounds__(SC_T) void k_scan2(const int* __restrict__ partial,
                                                int* __restrict__ base,
                                                int* __restrict__ off) {
    __shared__ int s[SC_T];
    int t = threadIdx.x;
    int v = (t < SC_B) ? partial[t] : 0;
    s[t] = v;
    __syncthreads();
    for (int d = 1; d < SC_T; d <<= 1) {
        int u = (t >= d) ? s[t - d] : 0;
        __syncthreads();
        s[t] += u;
        __syncthreads();
    }
    if (t < SC_B) base[t] = s[t] - v;
    if (t == SC_T - 1) off[N_ENT] = s[t];
}

// per-block rescan -> off, cur
__global__ __launch_bounds__(SC_T) void k_scan3(const int* __restrict__ deg,
                                                const int* __restrict__ base,
                                                int* __restrict__ off,
                                                int* __restrict__ cur) {
    __shared__ int s[SC_T];
    int b = blockIdx.x, t = threadIdx.x;
    int i0 = b * SC_CHUNK + t * SC_C;
    int d0 = deg[i0], d1 = deg[i0 + 1];
    int tsum = d0 + d1;
    s[t] = tsum;
    __syncthreads();
    for (int d = 1; d < SC_T; d <<= 1) {
        int u = (t >= d) ? s[t - d] : 0;
        __syncthreads();
        s[t] += u;
        __syncthreads();
    }
    int excl = s[t] - tsum + base[b];
    if (i0 < N_ENT)     { off[i0] = excl;          cur[i0] = excl; }
    if (i0 + 1 < N_ENT) { off[i0 + 1] = excl + d0; cur[i0 + 1] = excl + d0; }
}

// ---------------------------------------------------------------------------
// K6: per edge: w = exp(leaky(qh+qr+qt+ba2)); CSR-scatter packed (r,t) + w as float2
__global__ __launch_bounds__(256) void k_scatter(const int* __restrict__ trip,
                                                 const float* __restrict__ qh,
                                                 const float* __restrict__ qt,
                                                 const float* __restrict__ qr,
                                                 const float* __restrict__ ba2,
                                                 int* __restrict__ cur,
                                                 float2* __restrict__ pkw) {
    int e = blockIdx.x * 256 + threadIdx.x;
    if (e >= N_EDGES) return;
    int h  = trip[e * 3 + 0];
    int tl = trip[e * 3 + 1];
    int r  = trip[e * 3 + 2];
    float b = qh[h] + qt[tl] + qr[r] + ba2[0];
    float lr = b > 0.f ? b : 0.01f * b;
    float w = expf(lr);
    int pos = atomicAdd(&cur[h], 1);
    float2 v;
    v.x = __uint_as_float(((unsigned)r << 17) | (unsigned)tl);
    v.y = w;
    pkw[pos] = v;
}

// ---------------------------------------------------------------------------
// K7: per head (32 lanes): acc = sum w*(PR[r]+PTb[t]); out = elu((acc+sw*PHb[h])/sw')
// 4-deep unroll for MLP; PHb/PTb bf16, PR f32 (L2-resident).
__global__ __launch_bounds__(256) void k_gather(const int* __restrict__ off,
                                                const float2* __restrict__ pkw,
                                                const unsigned short* __restrict__ PHb,
                                                const float* __restrict__ PR,
                                                const unsigned short* __restrict__ PTb,
                                                float* __restrict__ out) {
    int idx = blockIdx.x * 256 + threadIdx.x;
    int i = idx >> 5, lane = idx & 31;
    if (i >= N_ENT) return;
    int lane4 = lane * 4;
    int e0 = off[i], e1 = off[i + 1];
    float4 acc = make_float4(0.f, 0.f, 0.f, 0.f);
    float sw = 0.f;
    int e = e0;
    for (; e + 3 < e1; e += 4) {
        float2 pw0 = pkw[e],     pw1 = pkw[e + 1];
        float2 pw2 = pkw[e + 2], pw3 = pkw[e + 3];
        unsigned p0 = __float_as_uint(pw0.x), p1 = __float_as_uint(pw1.x);
        unsigned p2 = __float_as_uint(pw2.x), p3 = __float_as_uint(pw3.x);
        ushort4 b0 = *(const ushort4*)&PTb[(size_t)(p0 & 0x1FFFFu) * DIM + lane4];
        ushort4 b1 = *(const ushort4*)&PTb[(size_t)(p1 & 0x1FFFFu) * DIM + lane4];
        ushort4 b2 = *(const ushort4*)&PTb[(size_t)(p2 & 0x1FFFFu) * DIM + lane4];
        ushort4 b3 = *(const ushort4*)&PTb[(size_t)(p3 & 0x1FFFFu) * DIM + lane4];
        float4 r0 = *(const float4*)&PR[(size_t)(p0 >> 17) * DIM + lane4];
        float4 r1 = *(const float4*)&PR[(size_t)(p1 >> 17) * DIM + lane4];
        float4 r2 = *(const float4*)&PR[(size_t)(p2 >> 17) * DIM + lane4];
        float4 r3 = *(const float4*)&PR[(size_t)(p3 >> 17) * DIM + lane4];
        float w0 = pw0.y, w1 = pw1.y, w2 = pw2.y, w3 = pw3.y;
        acc.x += w0 * (r0.x + bf2f(b0.x)) + w1 * (r1.x + bf2f(b1.x))
               + w2 * (r2.x + bf2f(b2.x)) + w3 * (r3.x + bf2f(b3.x));
        acc.y += w0 * (r0.y + bf2f(b0.y)) + w1 * (r1.y + bf2f(b1.y))
               + w2 * (r2.y + bf2f(b2.y)) + w3 * (r3.y + bf2f(b3.y));
        acc.z += w0 * (r0.z + bf2f(b0.z)) + w1 * (r1.z + bf2f(b1.z))
               + w2 * (r2.z + bf2f(b2.z)) + w3 * (r3.z + bf2f(b3.z));
        acc.w += w0 * (r0.w + bf2f(b0.w)) + w1 * (r1.w + bf2f(b1.w))
               + w2 * (r2.w + bf2f(b2.w)) + w3 * (r3.w + bf2f(b3.w));
        sw += (w0 + w1) + (w2 + w3);
    }
    for (; e < e1; ++e) {
        float2 pw = pkw[e];
        unsigned p = __float_as_uint(pw.x);
        float w = pw.y;
        ushort4 b = *(const ushort4*)&PTb[(size_t)(p & 0x1FFFFu) * DIM + lane4];
        float4 pr = *(const float4*)&PR[(size_t)(p >> 17) * DIM + lane4];
        acc.x += w * (pr.x + bf2f(b.x));
        acc.y += w * (pr.y + bf2f(b.y));
        acc.z += w * (pr.z + bf2f(b.z));
        acc.w += w * (pr.w + bf2f(b.w));
        sw += w;
    }
    ushort4 hb = *(const ushort4*)&PHb[(size_t)i * DIM + lane4];
    acc.x += sw * bf2f(hb.x);
    acc.y += sw * bf2f(hb.y);
    acc.z += sw * bf2f(hb.z);
    acc.w += sw * bf2f(hb.w);
    float den = (sw == 0.f) ? 1e-12f : sw;
    float inv = 1.f / den;
    float vx = acc.x * inv, vy = acc.y * inv, vz = acc.z * inv, vw = acc.w * inv;
    vx = vx > 0.f ? vx : expm1f(vx);
    vy = vy > 0.f ? vy : expm1f(vy);
    vz = vz > 0.f ? vz : expm1f(vz);
    vw = vw > 0.f ? vw : expm1f(vw);
    *(float4*)&out[(size_t)i * DIM + lane4] = make_float4(vx, vy, vz, vw);
}

// ---------------------------------------------------------------------------
extern "C" void kernel_launch(void* const* d_in, const int* in_sizes, int n_in,
                              void* d_out, int out_size, void* d_ws, size_t ws_size,
                              hipStream_t stream) {
    const int*   trip = (const int*)d_in[0];
    const float* ent  = (const float*)d_in[1];
    const float* rel  = (const float*)d_in[2];
    const float* Wa   = (const float*)d_in[3];
    const float* ba   = (const float*)d_in[4];
    const float* Wa2  = (const float*)d_in[5];
    const float* ba2  = (const float*)d_in[6];
    float* out = (float*)d_out;

    float* ws = (float*)d_ws;
    size_t o = 0;
    unsigned short* PHb = (unsigned short*)(ws + o); o += (size_t)N_ENT * DIM / 2;
    unsigned short* PTb = (unsigned short*)(ws + o); o += (size_t)N_ENT * DIM / 2;
    float* PR = ws + o;        o += (size_t)N_REL * DIM;
    float* qh = ws + o;        o += N_ENT;
    float* qt = ws + o;        o += N_ENT;
    float* qr = ws + o;        o += N_REL + 4;
    short* Bg = (short*)(ws + o);     o += 32768 / 2 + 8;
    int*   deg = (int*)(ws + o);      o += DEG_PAD;
    int*   off = (int*)(ws + o);      o += N_ENT + 1;
    int*   cur = (int*)(ws + o);      o += N_ENT + 1;
    int*   partial = (int*)(ws + o);  o += SC_T;
    int*   base = (int*)(ws + o);     o += SC_T;
    float2* pkw = (float2*)(ws + o);  o += (size_t)N_EDGES * 2;

    hipMemsetAsync(deg, 0, (size_t)DEG_PAD * sizeof(int), stream);

    k_prep<<<1, 512, 0, stream>>>(Wa, Bg);
    k_fused<<<ENT_BLKS + REL_BLKS, 512, 0, stream>>>(ent, Bg, Wa2, PHb, PTb, qh, qt,
                                                     trip, deg, rel, Wa, ba, PR, qr);
    k_scan1<<<SC_B, SC_T, 0, stream>>>(deg, partial);
    k_scan2<<<1, SC_T, 0, stream>>>(partial, base, off);
    k_scan3<<<SC_B, SC_T, 0, stream>>>(deg, base, off, cur);
    k_scatter<<<(N_EDGES + 255) / 256, 256, 0, stream>>>(trip, qh, qt, qr, ba2, cur, pkw);
    k_gather<<<(N_ENT * 32) / 256, 256, 0, stream>>>(off, pkw, PHb, PR, PTb, out);
}

// Round 12
// 177.099 us; speedup vs baseline: 10.0232x; 1.0368x over previous
//
#include <hip/hip_runtime.h>

#define N_ENT   100000
#define N_REL   500
#define N_EDGES 800000
#define DIM     128
#define WA_LD   384

#define MT       256
#define ENT_BLKS 391   // ceil(N_ENT/MT)
#define REL_BLKS 63    // 8 relations per block (8 waves), ceil(500/8)

// scan config
#define SC_T 256
#define SC_C 2
#define SC_CHUNK (SC_T * SC_C)                      // 512
#define SC_B ((N_ENT + SC_CHUNK - 1) / SC_CHUNK)    // 196
#define DEG_PAD (SC_B * SC_CHUNK)                   // 100352

typedef __attribute__((ext_vector_type(8))) short  s8v;   // 8 bf16 (4 VGPR)
typedef __attribute__((ext_vector_type(4))) float  f4v;   // MFMA acc

__device__ __forceinline__ unsigned short f2bf(float x) {
    unsigned u = __float_as_uint(x);
    return (unsigned short)((u + 0x7FFFu + ((u >> 16) & 1u)) >> 16);
}
__device__ __forceinline__ float bf2f(unsigned short h) {
    return __uint_as_float(((unsigned)h) << 16);
}

// ---------------------------------------------------------------------------
// K0: pre-convert [Wh | Wt] to bf16 in exact B-fragment order (one tiny block).
// B frag at lane l, elem e is B[kc*32 + (l>>4)*8 + e][nt*16 + (l&15)];
// stored at ((kc*16+nt)*64 + l)*8 + e.
__global__ __launch_bounds__(512) void k_prep(const float* __restrict__ Wa,
                                              short* __restrict__ Bg) {
    int t = threadIdx.x;
#pragma unroll
    for (int tt = 0; tt < 2; ++tt) {
#pragma unroll
        for (int it = 0; it < 4; ++it) {
            int g = t + 512 * it;        // 0..2047
            int j = g >> 4;              // col within table
            int k8 = g & 15;             // 8-float k-granule
            const float* src = Wa + (size_t)j * WA_LD + tt * 256 + k8 * 8;
            float4 v0 = *(const float4*)src;
            float4 v1 = *(const float4*)(src + 4);
            float x[8] = {v0.x, v0.y, v0.z, v0.w, v1.x, v1.y, v1.z, v1.w};
            s8v hv;
#pragma unroll
            for (int e = 0; e < 8; ++e) hv[e] = (short)f2bf(x[e]);
            int col = tt * 128 + j;
            int kc = k8 >> 2;
            int lanep = (k8 & 3) * 16 + (col & 15);
            int nt = col >> 4;
            *(s8v*)&Bg[((size_t)((kc * 16 + nt) * 64 + lanep)) * 8] = hv;
        }
    }
}

// ---------------------------------------------------------------------------
// K1 (fused): blocks [0,391): MFMA projection PHb/PTb (bf16) + fused qh/qt
//             + 4 edge-count atomics per thread (trip loads hoisted BEFORE the
//             MFMA loop so HBM latency hides under compute; atomics at end).
//             blocks [391,454): rel projection PR (f32) + qr, 1 wave/relation.
// Round 12: B fragments staged in LDS (64 KB bf16 single-copy, linear copy
// from pre-formatted Bg) -- round 11's L2-direct B feeds put ~250-cyc loads
// on the MFMA critical path (MfmaUtil 3%, 78 us).
__global__ __launch_bounds__(512) void k_fused(const float* __restrict__ ent,
                                               const short* __restrict__ Bg,
                                               const float* __restrict__ Wa2,
                                               unsigned short* __restrict__ PHb,
                                               unsigned short* __restrict__ PTb,
                                               float* __restrict__ qh,
                                               float* __restrict__ qt,
                                               const int* __restrict__ trip,
                                               int* __restrict__ deg,
                                               const float* __restrict__ rel,
                                               const float* __restrict__ Wa,
                                               const float* __restrict__ ba,
                                               float* __restrict__ PR,
                                               float* __restrict__ qr) {
    __shared__ s8v BsV[4096];        // 64 KB: B fragments, frag-ordered
    __shared__ float relLds[8][128]; // 4 KB: rel path
    int t = threadIdx.x;
    int wv = t >> 6;                 // wave 0..7
    int lane = t & 63;

    if (blockIdx.x >= ENT_BLKS) {
        // ---------------- rel path: relation r = rb*8 + wv ----------------
        int rb = blockIdx.x - ENT_BLKS;
        int r = rb * 8 + wv;
        if (r < N_REL) {
            relLds[wv][lane]      = rel[r * DIM + lane];
            relLds[wv][64 + lane] = rel[r * DIM + 64 + lane];
            int j0 = 2 * lane, j1 = j0 + 1;
            const float* w0 = Wa + (size_t)j0 * WA_LD + 128;
            const float* w1 = Wa + (size_t)j1 * WA_LD + 128;
            float a0 = ba[j0], a1 = ba[j1];
#pragma unroll 8
            for (int k4 = 0; k4 < 32; ++k4) {
                float4 rv = *(const float4*)&relLds[wv][4 * k4];
                float4 x0 = *(const float4*)&w0[4 * k4];
                float4 x1 = *(const float4*)&w1[4 * k4];
                a0 += rv.x * x0.x + rv.y * x0.y + rv.z * x0.z + rv.w * x0.w;
                a1 += rv.x * x1.x + rv.y * x1.y + rv.z * x1.z + rv.w * x1.w;
            }
            *(float2*)&PR[(size_t)r * DIM + j0] = make_float2(a0, a1);
            float p = a0 * Wa2[j0] + a1 * Wa2[j1];
#pragma unroll
            for (int m = 1; m <= 32; m <<= 1) p += __shfl_xor(p, m);
            if (lane == 0) qr[r] = p;
        }
        return;
    }

    // ---------------- ent path ----------------
    // stage B fragments: linear 64 KB copy (coalesced, conflict-free)
#pragma unroll
    for (int it = 0; it < 8; ++it) {
        int idx = t + 512 * it;      // 0..4095
        BsV[idx] = *(const s8v*)&Bg[(size_t)idx * 8];
    }

    // hoist trip-head loads for the fused count (latency hides under MFMA)
    int tid = blockIdx.x * 512 + t;
    int eb = tid * 4;
    int hh[4];
#pragma unroll
    for (int je = 0; je < 4; ++je) {
        int e = eb + je;
        hh[je] = (e < N_EDGES) ? trip[e * 3] : -1;
    }

    int l15 = lane & 15, lg = lane >> 4;
    int m0 = blockIdx.x * MT + wv * 32;

    f4v acc[2][16];
#pragma unroll
    for (int s = 0; s < 2; ++s)
#pragma unroll
        for (int nt = 0; nt < 16; ++nt)
            acc[s][nt] = (f4v){0.f, 0.f, 0.f, 0.f};

    __syncthreads();

#pragma unroll
    for (int kc = 0; kc < 4; ++kc) {
        s8v Ah[2];
#pragma unroll
        for (int s = 0; s < 2; ++s) {
            int row = m0 + s * 16 + l15;
            if (row < N_ENT) {
                const float* ap = ent + (size_t)row * DIM + kc * 32 + lg * 8;
                float4 v0 = *(const float4*)ap;
                float4 v1 = *(const float4*)(ap + 4);
                float x[8] = {v0.x, v0.y, v0.z, v0.w, v1.x, v1.y, v1.z, v1.w};
#pragma unroll
                for (int e = 0; e < 8; ++e) Ah[s][e] = (short)f2bf(x[e]);
            } else {
                Ah[s] = (s8v){0, 0, 0, 0, 0, 0, 0, 0};
            }
        }
#pragma unroll
        for (int nt = 0; nt < 16; ++nt) {
            s8v bg = BsV[(kc * 16 + nt) * 64 + lane];
            acc[0][nt] = __builtin_amdgcn_mfma_f32_16x16x32_bf16(Ah[0], bg, acc[0][nt], 0, 0, 0);
            acc[1][nt] = __builtin_amdgcn_mfma_f32_16x16x32_bf16(Ah[1], bg, acc[1][nt], 0, 0, 0);
        }
    }

    // epilogue: bf16 stores + fused qh/qt = P . Wa2 (tile nt -> Wa2 col (nt&7)*16+l15)
    float wa2v[8];
#pragma unroll
    for (int c8 = 0; c8 < 8; ++c8) wa2v[c8] = Wa2[c8 * 16 + l15];

#pragma unroll
    for (int s = 0; s < 2; ++s) {
        int rowb = m0 + s * 16 + lg * 4;
        float qhp[4] = {0.f, 0.f, 0.f, 0.f};
        float qtp[4] = {0.f, 0.f, 0.f, 0.f};
#pragma unroll
        for (int nt = 0; nt < 16; ++nt) {
#pragma unroll
            for (int g = 0; g < 4; ++g) {
                float v = acc[s][nt][g];
                if (nt < 8) qhp[g] += v * wa2v[nt];
                else        qtp[g] += v * wa2v[nt & 7];
                int row = rowb + g;
                if (row < N_ENT) {
                    if (nt < 8) PHb[(size_t)row * DIM + nt * 16 + l15] = f2bf(v);
                    else        PTb[(size_t)row * DIM + (nt - 8) * 16 + l15] = f2bf(v);
                }
            }
        }
#pragma unroll
        for (int g = 0; g < 4; ++g) {
            float a = qhp[g], b = qtp[g];
#pragma unroll
            for (int m = 1; m <= 8; m <<= 1) {
                a += __shfl_xor(a, m);
                b += __shfl_xor(b, m);
            }
            int row = rowb + g;
            if (l15 == 0 && row < N_ENT) { qh[row] = a; qt[row] = b; }
        }
    }

    // fused edge-count (h values already in registers)
#pragma unroll
    for (int je = 0; je < 4; ++je) {
        if (hh[je] >= 0) atomicAdd(&deg[hh[je]], 1);
    }
}

// ---------------------------------------------------------------------------
// scan: block partial sums
__global__ __launch_bounds__(SC_T) void k_scan1(const int* __restrict__ deg,
                                                int* __restrict__ partial) {
    int b = blockIdx.x, t = threadIdx.x;
    int i0 = b * SC_CHUNK + t * SC_C;
    int s = deg[i0] + deg[i0 + 1];
#pragma unroll
    for (int m = 1; m <= 32; m <<= 1) s += __shfl_xor(s, m);
    __shared__ int ws_[SC_T / 64];
    int lane = t & 63, wid = t >> 6;
    if (lane == 0) ws_[wid] = s;
    __syncthreads();
    if (t == 0) {
        int tot = 0;
        for (int w = 0; w < SC_T / 64; ++w) tot += ws_[w];
        partial[b] = tot;
    }
}

// scan of block partials (1 block)
__global__ __launch_bounds__(SC_T) void k_scan2(const int* __restrict__ partial,
                                                int* __restrict__ base,
                                                int* __restrict__ off) {
    __shared__ int s[SC_T];
    int t = threadIdx.x;
    int v = (t < SC_B) ? partial[t] : 0;
    s[t] = v;
    __syncthreads();
    for (int d = 1; d < SC_T; d <<= 1) {
        int u = (t >= d) ? s[t - d] : 0;
        __syncthreads();
        s[t] += u;
        __syncthreads();
    }
    if (t < SC_B) base[t] = s[t] - v;
    if (t == SC_T - 1) off[N_ENT] = s[t];
}

// per-block rescan -> off, cur
__global__ __launch_bounds__(SC_T) void k_scan3(const int* __restrict__ deg,
                                                const int* __restrict__ base,
                                                int* __restrict__ off,
                                                int* __restrict__ cur) {
    __shared__ int s[SC_T];
    int b = blockIdx.x, t = threadIdx.x;
    int i0 = b * SC_CHUNK + t * SC_C;
    int d0 = deg[i0], d1 = deg[i0 + 1];
    int tsum = d0 + d1;
    s[t] = tsum;
    __syncthreads();
    for (int d = 1; d < SC_T; d <<= 1) {
        int u = (t >= d) ? s[t - d] : 0;
        __syncthreads();
        s[t] += u;
        __syncthreads();
    }
    int excl = s[t] - tsum + base[b];
    if (i0 < N_ENT)     { off[i0] = excl;          cur[i0] = excl; }
    if (i0 + 1 < N_ENT) { off[i0 + 1] = excl + d0; cur[i0 + 1] = excl + d0; }
}

// ---------------------------------------------------------------------------
// K6: per edge: w = exp(leaky(qh+qr+qt+ba2)); CSR-scatter packed (r,t) + w as float2
__global__ __launch_bounds__(256) void k_scatter(const int* __restrict__ trip,
                                                 const float* __restrict__ qh,
                                                 const float* __restrict__ qt,
                                                 const float* __restrict__ qr,
                                                 const float* __restrict__ ba2,
                                                 int* __restrict__ cur,
                                                 float2* __restrict__ pkw) {
    int e = blockIdx.x * 256 + threadIdx.x;
    if (e >= N_EDGES) return;
    int h  = trip[e * 3 + 0];
    int tl = trip[e * 3 + 1];
    int r  = trip[e * 3 + 2];
    float b = qh[h] + qt[tl] + qr[r] + ba2[0];
    float lr = b > 0.f ? b : 0.01f * b;
    float w = expf(lr);
    int pos = atomicAdd(&cur[h], 1);
    float2 v;
    v.x = __uint_as_float(((unsigned)r << 17) | (unsigned)tl);
    v.y = w;
    pkw[pos] = v;
}

// ---------------------------------------------------------------------------
// K7: per head (32 lanes): acc = sum w*(PR[r]+PTb[t]); out = elu((acc+sw*PHb[h])/sw')
// 4-deep unroll for MLP; PHb/PTb bf16, PR f32 (L2-resident).
__global__ __launch_bounds__(256) void k_gather(const int* __restrict__ off,
                                                const float2* __restrict__ pkw,
                                                const unsigned short* __restrict__ PHb,
                                                const float* __restrict__ PR,
                                                const unsigned short* __restrict__ PTb,
                                                float* __restrict__ out) {
    int idx = blockIdx.x * 256 + threadIdx.x;
    int i = idx >> 5, lane = idx & 31;
    if (i >= N_ENT) return;
    int lane4 = lane * 4;
    int e0 = off[i], e1 = off[i + 1];
    float4 acc = make_float4(0.f, 0.f, 0.f, 0.f);
    float sw = 0.f;
    int e = e0;
    for (; e + 3 < e1; e += 4) {
        float2 pw0 = pkw[e],     pw1 = pkw[e + 1];
        float2 pw2 = pkw[e + 2], pw3 = pkw[e + 3];
        unsigned p0 = __float_as_uint(pw0.x), p1 = __float_as_uint(pw1.x);
        unsigned p2 = __float_as_uint(pw2.x), p3 = __float_as_uint(pw3.x);
        ushort4 b0 = *(const ushort4*)&PTb[(size_t)(p0 & 0x1FFFFu) * DIM + lane4];
        ushort4 b1 = *(const ushort4*)&PTb[(size_t)(p1 & 0x1FFFFu) * DIM + lane4];
        ushort4 b2 = *(const ushort4*)&PTb[(size_t)(p2 & 0x1FFFFu) * DIM + lane4];
        ushort4 b3 = *(const ushort4*)&PTb[(size_t)(p3 & 0x1FFFFu) * DIM + lane4];
        float4 r0 = *(const float4*)&PR[(size_t)(p0 >> 17) * DIM + lane4];
        float4 r1 = *(const float4*)&PR[(size_t)(p1 >> 17) * DIM + lane4];
        float4 r2 = *(const float4*)&PR[(size_t)(p2 >> 17) * DIM + lane4];
        float4 r3 = *(const float4*)&PR[(size_t)(p3 >> 17) * DIM + lane4];
        float w0 = pw0.y, w1 = pw1.y, w2 = pw2.y, w3 = pw3.y;
        acc.x += w0 * (r0.x + bf2f(b0.x)) + w1 * (r1.x + bf2f(b1.x))
               + w2 * (r2.x + bf2f(b2.x)) + w3 * (r3.x + bf2f(b3.x));
        acc.y += w0 * (r0.y + bf2f(b0.y)) + w1 * (r1.y + bf2f(b1.y))
               + w2 * (r2.y + bf2f(b2.y)) + w3 * (r3.y + bf2f(b3.y));
        acc.z += w0 * (r0.z + bf2f(b0.z)) + w1 * (r1.z + bf2f(b1.z))
               + w2 * (r2.z + bf2f(b2.z)) + w3 * (r3.z + bf2f(b3.z));
        acc.w += w0 * (r0.w + bf2f(b0.w)) + w1 * (r1.w + bf2f(b1.w))
               + w2 * (r2.w + bf2f(b2.w)) + w3 * (r3.w + bf2f(b3.w));
        sw += (w0 + w1) + (w2 + w3);
    }
    for (; e < e1; ++e) {
        float2 pw = pkw[e];
        unsigned p = __float_as_uint(pw.x);
        float w = pw.y;
        ushort4 b = *(const ushort4*)&PTb[(size_t)(p & 0x1FFFFu) * DIM + lane4];
        float4 pr = *(const float4*)&PR[(size_t)(p >> 17) * DIM + lane4];
        acc.x += w * (pr.x + bf2f(b.x));
        acc.y += w * (pr.y + bf2f(b.y));
        acc.z += w * (pr.z + bf2f(b.z));
        acc.w += w * (pr.w + bf2f(b.w));
        sw += w;
    }
    ushort4 hb = *(const ushort4*)&PHb[(size_t)i * DIM + lane4];
    acc.x += sw * bf2f(hb.x);
    acc.y += sw * bf2f(hb.y);
    acc.z += sw * bf2f(hb.z);
    acc.w += sw * bf2f(hb.w);
    float den = (sw == 0.f) ? 1e-12f : sw;
    float inv = 1.f / den;
    float vx = acc.x * inv, vy = acc.y * inv, vz = acc.z * inv, vw = acc.w * inv;
    vx = vx > 0.f ? vx : expm1f(vx);
    vy = vy > 0.f ? vy : expm1f(vy);
    vz = vz > 0.f ? vz : expm1f(vz);
    vw = vw > 0.f ? vw : expm1f(vw);
    *(float4*)&out[(size_t)i * DIM + lane4] = make_float4(vx, vy, vz, vw);
}

// ---------------------------------------------------------------------------
extern "C" void kernel_launch(void* const* d_in, const int* in_sizes, int n_in,
                              void* d_out, int out_size, void* d_ws, size_t ws_size,
                              hipStream_t stream) {
    const int*   trip = (const int*)d_in[0];
    const float* ent  = (const float*)d_in[1];
    const float* rel  = (const float*)d_in[2];
    const float* Wa   = (const float*)d_in[3];
    const float* ba   = (const float*)d_in[4];
    const float* Wa2  = (const float*)d_in[5];
    const float* ba2  = (const float*)d_in[6];
    float* out = (float*)d_out;

    float* ws = (float*)d_ws;
    size_t o = 0;
    unsigned short* PHb = (unsigned short*)(ws + o); o += (size_t)N_ENT * DIM / 2;
    unsigned short* PTb = (unsigned short*)(ws + o); o += (size_t)N_ENT * DIM / 2;
    float* PR = ws + o;        o += (size_t)N_REL * DIM;
    float* qh = ws + o;        o += N_ENT;
    float* qt = ws + o;        o += N_ENT;
    float* qr = ws + o;        o += N_REL + 4;
    short* Bg = (short*)(ws + o);     o += 32768 / 2 + 8;
    int*   deg = (int*)(ws + o);      o += DEG_PAD;
    int*   off = (int*)(ws + o);      o += N_ENT + 1;
    int*   cur = (int*)(ws + o);      o += N_ENT + 1;
    int*   partial = (int*)(ws + o);  o += SC_T;
    int*   base = (int*)(ws + o);     o += SC_T;
    float2* pkw = (float2*)(ws + o);  o += (size_t)N_EDGES * 2;

    hipMemsetAsync(deg, 0, (size_t)DEG_PAD * sizeof(int), stream);

    k_prep<<<1, 512, 0, stream>>>(Wa, Bg);
    k_fused<<<ENT_BLKS + REL_BLKS, 512, 0, stream>>>(ent, Bg, Wa2, PHb, PTb, qh, qt,
                                                     trip, deg, rel, Wa, ba, PR, qr);
    k_scan1<<<SC_B, SC_T, 0, stream>>>(deg, partial);
    k_scan2<<<1, SC_T, 0, stream>>>(partial, base, off);
    k_scan3<<<SC_B, SC_T, 0, stream>>>(deg, base, off, cur);
    k_scatter<<<(N_EDGES + 255) / 256, 256, 0, stream>>>(trip, qh, qt, qr, ba2, cur, pkw);
    k_gather<<<(N_ENT * 32) / 256, 256, 0, stream>>>(off, pkw, PHb, PR, PTb, out);
}